// Round 8
// baseline (549.612 us; speedup 1.0000x reference)
//
#include <hip/hip_runtime.h>
#include <hip/hip_bf16.h>
#include <math.h>

#define EMBED 1024
#define LSEQ 4096
#define BATCH 2
#define ZD 128
#define CHUNKC 2048
#define NSTATE 16
#define DTR 64
#define XDBL_W 96   // DT_RANK + 2*DSTATE
#define NSEG 64
#define TSEG 64     // LSEQ / NSEG

typedef __attribute__((ext_vector_type(8))) short bf16x8;
typedef __attribute__((ext_vector_type(4))) float f32x4;

__device__ __forceinline__ float sigmoidf_(float x){ return 1.f/(1.f+__expf(-x)); }
__device__ __forceinline__ float siluf_(float x){ return x/(1.f+__expf(-x)); }
__device__ __forceinline__ __hip_bfloat16 tobf(float x){ return __float2bfloat16(x); }
__device__ __forceinline__ float frombf(__hip_bfloat16 x){ return __bfloat162float(x); }

__device__ __forceinline__ void gload_lds16(const void* g, void* l) {
  __builtin_amdgcn_global_load_lds(
      (const __attribute__((address_space(1))) unsigned int*)g,
      (__attribute__((address_space(3))) unsigned int*)l, 16, 0, 0);
}

template<int N>
__device__ __forceinline__ void wait_vm(){
  if constexpr (N==0)      asm volatile("s_waitcnt vmcnt(0)" ::: "memory");
  else                     asm volatile("s_waitcnt vmcnt(8)" ::: "memory");
}

// ---------------------------------------------------------------- f32 -> bf16 converts (merged)
__global__ __launch_bounds__(256) void cvt3_k(const float* __restrict__ s0, __hip_bfloat16* __restrict__ d0, int n0,
                                              const float* __restrict__ s1, __hip_bfloat16* __restrict__ d1, int n1,
                                              const float* __restrict__ s2, __hip_bfloat16* __restrict__ d2, int n2) {
  int i = (blockIdx.x*256 + threadIdx.x)*4;
  const float* s; __hip_bfloat16* d;
  if (i < n0) { s = s0 + i; d = d0 + i; }
  else if (i < n0+n1) { s = s1 + (i-n0); d = d1 + (i-n0); }
  else if (i < n0+n1+n2) { s = s2 + (i-n0-n1); d = d2 + (i-n0-n1); }
  else return;
  float4 v = *(const float4*)s;
  d[0]=tobf(v.x); d[1]=tobf(v.y); d[2]=tobf(v.z); d[3]=tobf(v.w);
}

// zero-padded convert (rows >= srcRows -> 0)
__global__ __launch_bounds__(256) void cvt_pad_k(const float* __restrict__ s,
                                                 __hip_bfloat16* __restrict__ d,
                                                 int srcRows, int cols, int dstRows) {
  int idx = blockIdx.x*256 + threadIdx.x;
  if (idx >= dstRows*cols) return;
  int r = idx / cols;
  d[idx] = tobf(r < srcRows ? s[idx] : 0.f);
}

// ---------------------------------------------------------------- rmsnorm (dual out: f32 + bf16)
__global__ __launch_bounds__(256) void rmsnorm_k(const float* __restrict__ x,
                                                 const float* __restrict__ w,
                                                 float* __restrict__ xn,
                                                 __hip_bfloat16* __restrict__ xnb) {
  size_t row = blockIdx.x;
  const float* px = x + row*EMBED;
  int tid = threadIdx.x;
  float4 xv = *(const float4*)(px + tid*4);
  float ss = xv.x*xv.x + xv.y*xv.y + xv.z*xv.z + xv.w*xv.w;
  #pragma unroll
  for (int off=32; off; off>>=1) ss += __shfl_down(ss, off, 64);
  __shared__ float red[4];
  if ((tid&63)==0) red[tid>>6]=ss;
  __syncthreads();
  float tot = red[0]+red[1]+red[2]+red[3];
  float scale = rsqrtf(tot*(1.f/EMBED) + 1e-5f);
  float4 wv = *(const float4*)(w + tid*4);
  float4 o;
  o.x=xv.x*scale*wv.x; o.y=xv.y*scale*wv.y; o.z=xv.z*scale*wv.z; o.w=xv.w*scale*wv.w;
  *(float4*)(xn + row*EMBED + tid*4) = o;
  __hip_bfloat16* pb = xnb + row*EMBED + tid*4;
  pb[0]=tobf(o.x); pb[1]=tobf(o.y); pb[2]=tobf(o.z); pb[3]=tobf(o.w);
}

// ---------------------------------------------------------------- gtab (Toeplitz rel-pos bias)
__global__ __launch_bounds__(256) void gtab_k(const float* __restrict__ alpha,
                                              const float* __restrict__ beta,
                                              float* __restrict__ gtab) {
  __shared__ float P[64], Q[64], F[64];
  int tid = threadIdx.x;
  if (tid < 64) {
    float a1=alpha[tid], a2=alpha[64+tid], b1=beta[tid], b2=beta[64+tid];
    P[tid]=a1*b1+a2*b2;
    Q[tid]=a2*b1-a1*b2;
    F[tid]=expf(-0.14391156831f*(float)tid); // ln(10000)/64
  }
  __syncthreads();
  int d = blockIdx.x*256 + tid;
  if (d < CHUNKC) {
    float s=0.f;
    for (int j=0;j<64;++j){
      float th = (float)d * F[j];
      float sn, cs;
      sincosf(th, &sn, &cs);
      s += P[j]*cs - Q[j]*sn;
    }
    gtab[d]=s;
  }
}

// ---------------------------------------------------------------- segment-parallel S6 scan
template<bool FINAL>
__global__ __launch_bounds__(256) void seg_scan_k(
    const float* __restrict__ xdbl,
    const float* __restrict__ dtv,
    const float* __restrict__ xn,
    const float* __restrict__ A_log,
    const float* __restrict__ D_p,
    const float* __restrict__ segInit,
    float* __restrict__ segP,
    float* __restrict__ segH,
    __hip_bfloat16* __restrict__ mx)
{
  int bx = blockIdx.x;
  int seg = bx >> 3;
  int grp = bx & 7;
  int b = grp >> 2;
  int d = (grp & 3)*256 + threadIdx.x;
  int ch = b*EMBED + d;
  int tid = threadIdx.x;
  int tbase = seg*TSEG;

  float A[NSTATE], h[NSTATE], P[NSTATE];
  #pragma unroll
  for (int n=0;n<NSTATE;++n){
    A[n] = -__expf(A_log[(size_t)d*NSTATE+n]);
    P[n] = 1.f;
  }
  if (FINAL) {
    const float* si = segInit + ((size_t)seg*2048 + ch)*NSTATE;
    #pragma unroll
    for (int n=0;n<NSTATE;++n) h[n] = si[n];
  } else {
    #pragma unroll
    for (int n=0;n<NSTATE;++n) h[n] = 0.f;
  }
  float Dp = FINAL ? D_p[d] : 0.f;

  __shared__ float BCb[8][32];
  const float* xd  = xdbl + ((size_t)b*LSEQ + tbase)*XDBL_W + DTR;
  const float* pdt = dtv + ((size_t)b*LSEQ + tbase)*EMBED + d;
  const float* pu  = xn  + ((size_t)b*LSEQ + tbase)*EMBED + d;
  __hip_bfloat16* pmx = mx + ((size_t)b*LSEQ + tbase)*EMBED + d;

  for (int t0=0; t0<TSEG; t0+=8) {
    __syncthreads();
    { int tt = tid>>5, jj = tid&31;
      BCb[tt][jj] = xd[(size_t)(t0+tt)*XDBL_W + jj]; }
    __syncthreads();
    #pragma unroll
    for (int tt=0; tt<8; ++tt) {
      int t = t0 + tt;
      float dtt = pdt[(size_t)t*EMBED];
      float ut  = pu[(size_t)t*EMBED];
      float du = dtt*ut;
      float y = 0.f;
      #pragma unroll
      for (int n=0;n<NSTATE;++n){
        float dA = __expf(dtt*A[n]);
        h[n] = dA*h[n] + du*BCb[tt][n];
        if (!FINAL) P[n] *= dA;
        if (FINAL)  y += h[n]*BCb[tt][16+n];
      }
      if (FINAL) pmx[(size_t)t*EMBED] = tobf(siluf_(y + ut*Dp));
    }
  }
  if (!FINAL) {
    float* pp = segP + ((size_t)seg*2048 + ch)*NSTATE;
    float* ph = segH + ((size_t)seg*2048 + ch)*NSTATE;
    #pragma unroll
    for (int n=0;n<NSTATE;n+=4){
      *(float4*)(pp+n) = make_float4(P[n],P[n+1],P[n+2],P[n+3]);
      *(float4*)(ph+n) = make_float4(h[n],h[n+1],h[n+2],h[n+3]);
    }
  }
}

__global__ __launch_bounds__(256) void seg_combine_k(const float* __restrict__ segP,
                                                     const float* __restrict__ segH,
                                                     float* __restrict__ segInit) {
  int idx = blockIdx.x*256 + threadIdx.x;
  float H = 0.f;
  for (int s=0; s<NSEG; ++s) {
    size_t o = (size_t)s*32768 + idx;
    float Pv = segP[o], hl = segH[o];
    segInit[o] = H;
    H = Pv*H + hl;
  }
}

// ---------------------------------------------------------------- row softmax (bf16 in, bf16 out), causal-aware
__global__ __launch_bounds__(256) void softmax_k(const __hip_bfloat16* __restrict__ S,
                                                 __hip_bfloat16* __restrict__ Sb) {
  size_t row = blockIdx.x;
  const __hip_bfloat16* p = S + row*CHUNKC;
  __hip_bfloat16* po = Sb + row*CHUNKC;
  int tid = threadIdx.x;
  int r = (int)(row & (CHUNKC-1));
  int nb = (r >> 8) + 1;
  float v[8];
  float m = -1e30f;
  #pragma unroll
  for (int i=0;i<8;++i){
    if (i < nb) {
      float t = frombf(p[tid + i*256]);
      v[i] = (i*256 + tid <= r) ? t : -1e30f;
    } else v[i] = -1e30f;
    m = fmaxf(m, v[i]);
  }
  #pragma unroll
  for (int off=32; off; off>>=1) m = fmaxf(m, __shfl_down(m, off, 64));
  __shared__ float red[4];
  if ((tid&63)==0) red[tid>>6]=m;
  __syncthreads();
  m = fmaxf(fmaxf(red[0],red[1]),fmaxf(red[2],red[3]));
  float s=0.f;
  #pragma unroll
  for (int i=0;i<8;++i){ v[i]=__expf(v[i]-m); s+=v[i]; }
  #pragma unroll
  for (int off=32; off; off>>=1) s += __shfl_down(s, off, 64);
  __syncthreads();
  if ((tid&63)==0) red[tid>>6]=s;
  __syncthreads();
  s = red[0]+red[1]+red[2]+red[3];
  float inv = 1.f/s;
  #pragma unroll
  for (int i=0;i<8;++i) po[tid + i*256] = tobf(v[i]*inv);
}

// ---------------------------------------------------------------- bf16 transpose V -> VT[c][n][k]
__global__ __launch_bounds__(256) void transpose_k(const unsigned short* __restrict__ vb,
                                                   unsigned short* __restrict__ VT) {
  __shared__ unsigned short t[64][68];
  int tid = threadIdx.x;
  int tr = tid>>4;
  int tc = (tid&15)*4;
  int c0 = blockIdx.x*64, r0 = blockIdx.y*64;
  #pragma unroll
  for (int it=0; it<4; ++it) {
    int r = it*16 + tr;
    ushort4 v = *(const ushort4*)(vb + (size_t)(r0+r)*EMBED + c0 + tc);
    t[r][tc+0]=v.x; t[r][tc+1]=v.y; t[r][tc+2]=v.z; t[r][tc+3]=v.w;
  }
  __syncthreads();
  int ch = r0 >> 11;
  int kb = r0 & 2047;
  #pragma unroll
  for (int it=0; it<4; ++it) {
    int nl = it*16 + tr;
    ushort4 o;
    o.x = t[tc+0][nl]; o.y = t[tc+1][nl]; o.z = t[tc+2][nl]; o.w = t[tc+3][nl];
    *(ushort4*)(VT + ((size_t)ch*EMBED + c0 + nl)*CHUNKC + kb + tc) = o;
  }
}

// ---------------------------------------------------------------- epilogue params
struct MEp {
  const float* bias; const float* gtab; const float* gamma; const float* beta2;
  __hip_bfloat16* ug; __hip_bfloat16* qo; __hip_bfloat16* ko; __hip_bfloat16* ro; __hip_bfloat16* hxo;
  const __hip_bfloat16* rb; const __hip_bfloat16* hxb; const __hip_bfloat16* ub;
  const float* resid; float* outp;
  __hip_bfloat16* Cb; int ldc;
  float* f32o; __hip_bfloat16* bf16o;
};

__device__ __forceinline__ void xcd_swz(int& bx, int& by) {
  const int gx = gridDim.x;
  const int nwg = gx*gridDim.y;
  const int lin = by*gx + bx;
  const int qq = nwg >> 3, rr = nwg & 7;
  const int xcd = lin & 7, pos = lin >> 3;
  const int base = (xcd < rr) ? xcd*(qq+1) : rr*(qq+1) + (xcd-rr)*qq;
  const int lg = base + pos;
  bx = lg % gx; by = lg / gx;
}

// ---------------------------------------------------------------- 128x128 2-phase MFMA GEMM (short-K ops)
// EPI: 2 QK bias+mask->bf16 (upper tiles skipped, upper stores skipped);
//      5 xdbl dual; 6 dt softplus->f32
#define MBM 128
#define MBK 64

template<int EPI, bool SWZ>
__global__ __launch_bounds__(256) void mgemm_k(
    const __hip_bfloat16* __restrict__ A, int lda, long long sAz,
    const __hip_bfloat16* __restrict__ B, int ldb, long long sBz,
    int K, MEp ep)
{
  __shared__ __attribute__((aligned(16))) short As[2][MBM*MBK];
  __shared__ __attribute__((aligned(16))) short Bs[2][MBM*MBK];
  const int tid = threadIdx.x;
  const int wv = tid>>6, lane = tid&63;
  const int z = blockIdx.z;
  A += (size_t)z * sAz;
  B += (size_t)z * sBz;
  int bx = blockIdx.x, by = blockIdx.y;
  if constexpr (SWZ) xcd_swz(bx, by);
  const int m0 = by*MBM, n0 = bx*MBM;
  if constexpr (EPI==2) { if (n0 > m0 + (MBM-1)) return; }
  const int r8 = lane>>3, g8 = lane&7;
  const int csrc = g8 ^ r8;
  const int wr = wv>>1, wc = wv&1;
  const int fr = lane&15, qv = lane>>4;
  const int x7 = fr & 7;

  const int nt = K / MBK;
  f32x4 acc[4][4] = {};

  const __hip_bfloat16* Ag = A + (size_t)(m0 + wv*32 + r8)*lda + csrc*8;
  const __hip_bfloat16* Bg = B + (size_t)(n0 + wv*32 + r8)*ldb + csrc*8;

  auto stage = [&](int buf, int t){
    const int k0 = t*MBK;
    short* Al = &As[buf][wv*32*MBK];
    short* Bl = &Bs[buf][wv*32*MBK];
    #pragma unroll
    for (int j=0;j<4;++j)
      gload_lds16(Ag + (size_t)(j*8)*lda + k0, Al + j*8*MBK);
    #pragma unroll
    for (int j=0;j<4;++j)
      gload_lds16(Bg + (size_t)(j*8)*ldb + k0, Bl + j*8*MBK);
  };

  stage(0, 0);
  if (nt > 1) { stage(1, 1); wait_vm<8>(); }
  else wait_vm<0>();
  __builtin_amdgcn_sched_barrier(0);
  __builtin_amdgcn_s_barrier();

  for (int t=0; t<nt; ++t) {
    const int cur = t & 1;
    const short* Ab = &As[cur][0];
    const short* Bb = &Bs[cur][0];
    #pragma unroll
    for (int kk=0; kk<2; ++kk) {
      const int pos8 = ((kk*4 + qv) ^ x7) * 8;
      bf16x8 af[4], bfr[4];
      #pragma unroll
      for (int mi=0;mi<4;++mi)
        af[mi] = *(const bf16x8*)&Ab[(wr*64 + mi*16 + fr)*MBK + pos8];
      #pragma unroll
      for (int ni=0;ni<4;++ni)
        bfr[ni] = *(const bf16x8*)&Bb[(wc*64 + ni*16 + fr)*MBK + pos8];
      #pragma unroll
      for (int mi=0;mi<4;++mi)
        #pragma unroll
        for (int ni=0;ni<4;++ni)
          acc[mi][ni] = __builtin_amdgcn_mfma_f32_16x16x32_bf16(af[mi], bfr[ni], acc[mi][ni], 0,0,0);
    }
    if (t+1 >= nt) break;
    __builtin_amdgcn_sched_barrier(0);
    __builtin_amdgcn_s_barrier();
    if (t+2 < nt) { stage(cur, t+2); wait_vm<8>(); }
    else wait_vm<0>();
    __builtin_amdgcn_sched_barrier(0);
    __builtin_amdgcn_s_barrier();
    __builtin_amdgcn_sched_barrier(0);
  }

  const int vr = (lane>>4)*4;
  #pragma unroll
  for (int mi=0;mi<4;++mi) {
    #pragma unroll
    for (int v=0; v<4; ++v) {
      const int row = m0 + wr*64 + mi*16 + vr + v;
      #pragma unroll
      for (int ni=0;ni<4;++ni) {
        const int col = n0 + wc*64 + ni*16 + fr;
        float val = acc[mi][ni][v];
        if constexpr (EPI==2) {
          __hip_bfloat16* Sp = ep.Cb + (size_t)z*CHUNKC*CHUNKC;
          if (col <= row) Sp[(size_t)row*CHUNKC + col] = tobf(val + ep.gtab[row-col]);
        } else if constexpr (EPI==5) {
          if (col < XDBL_W) ep.f32o[(size_t)row*XDBL_W + col] = val;
          if (col < DTR)    ep.bf16o[(size_t)row*DTR + col] = tobf(val);
        } else {
          float zv = val + ep.bias[col];
          ep.f32o[(size_t)row*EMBED + col] = (zv > 15.f) ? zv : log1pf(__expf(zv));
        }
      }
    }
  }
}

// ---------------------------------------------------------------- 256-row recipe-form MFMA GEMM (big ops)
// T3 minimum recipe: STAGE(next) issued FIRST, then per-kk {ds_read, lgkmcnt(0),
// setprio MFMA}, then ONE vmcnt(0)+s_barrier per K-step. BM=256, BNT in {256,128},
// 8 waves (2 row x 4 col), same XOR staging/read swizzle (0 conflicts measured).
// EPI: 0 silu+bias->bf16; 1 base-split (col<Nreal guard); 3 PV*r->bf16 (TRIK); 4 final gate
template<int EPI, int BNT, bool TRIK>
__global__ __launch_bounds__(512) void m256r_k(
    const __hip_bfloat16* __restrict__ A, int lda, long long sAz,
    const __hip_bfloat16* __restrict__ B, int ldb, long long sBz,
    int K, int Nreal, MEp ep)
{
  constexpr int NI = BNT/64;        // B fragments per kk per wave
  __shared__ __attribute__((aligned(16))) short As[2][256*64];
  __shared__ __attribute__((aligned(16))) short Bs[2][BNT*64];
  const int tid = threadIdx.x;
  const int wid = tid>>6, lane = tid&63;
  const int z = blockIdx.z;
  A += (size_t)z * sAz;
  B += (size_t)z * sBz;
  int bx = blockIdx.x, by = blockIdx.y;
  xcd_swz(bx, by);
  const int m0 = by*256, n0 = bx*BNT;
  const int r8 = lane>>3, g8 = lane&7;
  const int csrc = g8 ^ r8;
  const int fr = lane&15, qv = lane>>4;
  const int x7 = fr & 7;
  const int wr2 = wid>>2, wc4 = wid&3;

  int Ktot = K;
  if constexpr (TRIK) { int km = m0 + 256; Ktot = km < K ? km : K; }
  const int nt = Ktot / 64;

  f32x4 acc[8][NI] = {};

  const __hip_bfloat16* Ag = A + (size_t)(m0 + wid*32 + r8)*lda + csrc*8;
  const __hip_bfloat16* Bg = B + (size_t)(n0 + wid*(BNT/8) + r8)*ldb + csrc*8;

  auto stage = [&](int buf, int t){
    const int k0 = t*64;
    #pragma unroll
    for (int j=0;j<4;++j)
      gload_lds16(Ag + (size_t)(j*8)*lda + k0, &As[buf][(wid*32 + j*8)*64]);
    #pragma unroll
    for (int j=0;j<NI;++j)
      gload_lds16(Bg + (size_t)(j*8)*ldb + k0, &Bs[buf][(wid*(BNT/8) + j*8)*64]);
  };

  // prologue per recipe: STAGE(buf0, t=0); vmcnt(0); barrier
  stage(0, 0);
  wait_vm<0>();
  __builtin_amdgcn_sched_barrier(0);
  __builtin_amdgcn_s_barrier();

  int cur = 0;
  for (int t=0; t<nt; ++t) {
    if (t+1 < nt) stage(cur^1, t+1);     // issue next-tile loads FIRST (latency hides under compute)
    const short* Ab = &As[cur][0];
    const short* Bb = &Bs[cur][0];
    #pragma unroll
    for (int kk=0; kk<2; ++kk) {
      const int pos8 = ((kk*4 + qv) ^ x7) * 8;
      bf16x8 af[8], bfr[NI];
      #pragma unroll
      for (int mi=0;mi<8;++mi)
        af[mi] = *(const bf16x8*)&Ab[(wr2*128 + mi*16 + fr)*64 + pos8];
      #pragma unroll
      for (int ni=0;ni<NI;++ni)
        bfr[ni] = *(const bf16x8*)&Bb[(wc4*(BNT/4) + ni*16 + fr)*64 + pos8];
      asm volatile("s_waitcnt lgkmcnt(0)" ::: "memory");
      __builtin_amdgcn_sched_barrier(0);
      __builtin_amdgcn_s_setprio(1);
      #pragma unroll
      for (int mi=0;mi<8;++mi)
        #pragma unroll
        for (int ni=0;ni<NI;++ni)
          acc[mi][ni] = __builtin_amdgcn_mfma_f32_16x16x32_bf16(af[mi], bfr[ni], acc[mi][ni], 0,0,0);
      __builtin_amdgcn_s_setprio(0);
      __builtin_amdgcn_sched_barrier(0);
    }
    if (t+1 < nt) wait_vm<0>();          // next tile landed (drain hidden under this tile's compute)
    __builtin_amdgcn_sched_barrier(0);
    __builtin_amdgcn_s_barrier();        // ONE barrier per K-step
    cur ^= 1;
  }

  const int vr = qv*4;
  #pragma unroll
  for (int mi=0;mi<8;++mi) {
    #pragma unroll
    for (int v=0; v<4; ++v) {
      const int row = m0 + wr2*128 + mi*16 + vr + v;
      #pragma unroll
      for (int ni=0;ni<NI;++ni) {
        const int col = n0 + wc4*(BNT/4) + ni*16 + fr;
        float val = acc[mi][ni][v];
        if constexpr (EPI==0) {
          ep.Cb[(size_t)row*ep.ldc + col] = tobf(siluf_(val + ep.bias[col]));
        } else if constexpr (EPI==1) {
          if (col < Nreal) {
            val += ep.bias[col];
            if (col < 1024) {
              ep.ug[(size_t)row*EMBED + col] = tobf(sigmoidf_(val));
            } else if (col < 1152) {
              int jj = col - 1024;
              float zz = siluf_(val);
              ep.qo[(size_t)row*ZD + jj] = tobf((zz*ep.gamma[jj] + ep.beta2[jj]) * 0.08838834764831845f);
              ep.ko[(size_t)row*ZD + jj] = tobf(zz*ep.gamma[128+jj] + ep.beta2[128+jj]);
            } else if (col < 2176) {
              ep.ro[(size_t)row*EMBED + (col-1152)] = tobf(siluf_(val));
            } else {
              ep.hxo[(size_t)row*EMBED + (col-2176)] = tobf(val);
            }
          }
        } else if constexpr (EPI==3) {
          size_t gr = (size_t)z*CHUNKC + row;
          ep.Cb[gr*EMBED + col] = tobf(val * frombf(ep.rb[gr*EMBED + col]));
        } else {
          float zz = val + ep.bias[col] + frombf(ep.hxb[(size_t)row*EMBED + col]);
          float hh = siluf_(zz);
          float res = ep.resid[(size_t)row*EMBED + col];
          ep.outp[(size_t)row*EMBED + col] = res + frombf(ep.ub[(size_t)row*EMBED + col])*(hh-res);
        }
      }
    }
  }
}

// ---------------------------------------------------------------- launch
extern "C" void kernel_launch(void* const* d_in, const int* in_sizes, int n_in,
                              void* d_out, int out_size, void* d_ws, size_t ws_size,
                              hipStream_t stream) {
  const float* x       = (const float*)d_in[0];
  const float* norm_w  = (const float*)d_in[1];
  const float* v_w     = (const float*)d_in[2];
  const float* v_b     = (const float*)d_in[3];
  const float* mx_w    = (const float*)d_in[4];
  const float* mx_b    = (const float*)d_in[5];
  const float* h_w     = (const float*)d_in[6];
  const float* h_b     = (const float*)d_in[7];
  const float* gamma   = (const float*)d_in[8];
  const float* beta    = (const float*)d_in[9];
  const float* alpha_rb= (const float*)d_in[10];
  const float* beta_rb = (const float*)d_in[11];
  const float* xproj_w = (const float*)d_in[12];
  const float* dt_w    = (const float*)d_in[13];
  const float* dt_b    = (const float*)d_in[14];
  const float* A_log   = (const float*)d_in[15];
  const float* D_p     = (const float*)d_in[16];
  float* out = (float*)d_out;

  float* ws = (float*)d_ws;
  size_t off = 0;
  auto alloc = [&](size_t n){ float* p = ws + off; off += n; return p; };
  const size_t BL2 = (size_t)BATCH*LSEQ; // 8192

  float* xn      = alloc(BL2*EMBED);        // f32; later aliased by Sb
  float* scratch = alloc((size_t)2*CHUNKC*CHUNKC*2); // dtb+seg*, then S(bf16)
  float* xdbl    = alloc(BL2*XDBL_W);
  float* gtab    = alloc(CHUNKC);
  auto balloc = [&](size_t nbf){ __hip_bfloat16* p = (__hip_bfloat16*)(ws + off); off += (nbf+1)/2; return p; };
  __hip_bfloat16* xnb   = balloc(BL2*EMBED);   // later reused as VT
  __hip_bfloat16* vbufb = balloc(BL2*EMBED);
  __hip_bfloat16* mxb   = balloc(BL2*EMBED);
  __hip_bfloat16* qb    = balloc(BL2*ZD);
  __hip_bfloat16* kb    = balloc(BL2*ZD);
  __hip_bfloat16* ugb   = balloc(BL2*EMBED);
  __hip_bfloat16* rbb   = balloc(BL2*EMBED);
  __hip_bfloat16* hxbb  = balloc(BL2*EMBED);
  __hip_bfloat16* hrb   = balloc(BL2*EMBED);
  __hip_bfloat16* xdblb = balloc(BL2*DTR);
  __hip_bfloat16* vwb   = balloc((size_t)EMBED*EMBED);
  __hip_bfloat16* mxwb  = balloc((size_t)3328*EMBED);  // padded 3200->3328 rows
  __hip_bfloat16* hwb   = balloc((size_t)EMBED*EMBED);
  __hip_bfloat16* xpwb  = balloc((size_t)128*EMBED);   // xproj_w padded 96->128 rows
  __hip_bfloat16* dtwb  = balloc((size_t)EMBED*DTR);

  float* dtb     = scratch;
  float* segP    = scratch + BL2*EMBED;
  float* segH    = segP + (size_t)NSEG*2048*NSTATE;
  float* segInit = segH + (size_t)NSEG*2048*NSTATE;
  __hip_bfloat16* S  = (__hip_bfloat16*)scratch;  // after scan (bf16 4*2048*2048)
  __hip_bfloat16* Sb = (__hip_bfloat16*)xn;       // after scan
  __hip_bfloat16* VT = xnb;                       // after v + xdbl GEMMs

  // 0. weight conversions + bias table
  cvt3_k<<<(2*EMBED*EMBED + EMBED*DTR + 1023)/1024, 256, 0, stream>>>(
      v_w, vwb, EMBED*EMBED, h_w, hwb, EMBED*EMBED, dt_w, dtwb, EMBED*DTR);
  cvt_pad_k<<<(3328*EMBED+255)/256, 256, 0, stream>>>(mx_w, mxwb, 3200, EMBED, 3328);
  cvt_pad_k<<<(128*EMBED+255)/256, 256, 0, stream>>>(xproj_w, xpwb, XDBL_W, EMBED, 128);
  gtab_k<<<CHUNKC/256, 256, 0, stream>>>(alpha_rb, beta_rb, gtab);

  // 1. rmsnorm
  rmsnorm_k<<<(int)BL2, 256, 0, stream>>>(x, norm_w, xn, xnb);

  MEp ep;

  // 2. v = silu(xn @ v_w^T + v_b)  [bf16]  (256x128 tiles -> 256 blocks)
  ep = {}; ep.bias = v_b; ep.Cb = vbufb; ep.ldc = EMBED;
  m256r_k<0,128,false><<<dim3(EMBED/128, BL2/256), 512, 0, stream>>>(
      xnb, EMBED, 0, vwb, EMBED, 0, EMBED, EMBED, ep);

  // 3. xdbl = xn @ xproj_w^T  (f32 96 cols + bf16 first 64)
  ep = {}; ep.f32o = xdbl; ep.bf16o = xdblb;
  mgemm_k<5,false><<<dim3(1, BL2/MBM), 256, 0, stream>>>(
      xnb, EMBED, 0, xpwb, EMBED, 0, EMBED, ep);

  // 4. dt = softplus(xdbl[:, :64] @ dt_w^T + dt_b)  (f32)
  ep = {}; ep.bias = dt_b; ep.f32o = dtb;
  mgemm_k<6,true><<<dim3(EMBED/MBM, BL2/MBM), 256, 0, stream>>>(
      xdblb, DTR, 0, dtwb, DTR, 0, DTR, ep);

  // 2b. transpose V per chunk (xnb dead now)
  transpose_k<<<dim3(EMBED/64, BL2/64), 256, 0, stream>>>(
      (const unsigned short*)vbufb, (unsigned short*)VT);

  // 5. segment-parallel scan -> mxb
  seg_scan_k<false><<<NSEG*8, 256, 0, stream>>>(xdbl, dtb, xn, A_log, D_p,
                                                nullptr, segP, segH, nullptr);
  seg_combine_k<<<128, 256, 0, stream>>>(segP, segH, segInit);
  seg_scan_k<true><<<NSEG*8, 256, 0, stream>>>(xdbl, dtb, xn, A_log, D_p,
                                               segInit, nullptr, nullptr, mxb);

  // 6. base = mx @ mx_w^T + mx_b, split epilogue (256x256 tiles -> 416 blocks)
  ep = {}; ep.bias = mx_b; ep.gamma = gamma; ep.beta2 = beta;
  ep.ug = ugb; ep.qo = qb; ep.ko = kb; ep.ro = rbb; ep.hxo = hxbb;
  m256r_k<1,256,false><<<dim3(3328/256, BL2/256), 512, 0, stream>>>(
      mxb, EMBED, 0, mxwb, EMBED, 0, EMBED, 3200, ep);

  // 7. QK^T + bias + mask -> bf16 S (upper-triangle tiles + stores skipped)
  ep = {}; ep.gtab = gtab; ep.Cb = S;
  mgemm_k<2,true><<<dim3(CHUNKC/MBM, CHUNKC/MBM, 4), 256, 0, stream>>>(
      qb, ZD, (long long)CHUNKC*ZD, kb, ZD, (long long)CHUNKC*ZD, ZD, ep);

  // 8. softmax (causal-aware reads, bf16 in/out)
  softmax_k<<<4*CHUNKC, 256, 0, stream>>>(S, Sb);

  // 9. P@V, K clipped to diagonal, fused *r -> bf16 (256x128 tiles -> 256 blocks)
  ep = {}; ep.rb = rbb; ep.Cb = hrb;
  m256r_k<3,128,true><<<dim3(EMBED/128, CHUNKC/256, 4), 512, 0, stream>>>(
      Sb, CHUNKC, (long long)CHUNKC*CHUNKC, VT, CHUNKC, (long long)EMBED*CHUNKC, CHUNKC, EMBED, ep);

  // 10. final: h = silu(hx + (h*r) @ h_w^T + h_b); out = x + u*(h-x)
  ep = {}; ep.bias = h_b; ep.hxb = hxbb; ep.ub = ugb; ep.resid = x; ep.outp = out;
  m256r_k<4,128,false><<<dim3(EMBED/128, BL2/256), 512, 0, stream>>>(
      hrb, EMBED, 0, hwb, EMBED, 0, EMBED, EMBED, ep);
}

// Round 9
// 508.662 us; speedup vs baseline: 1.0805x; 1.0805x over previous
//
#include <hip/hip_runtime.h>
#include <hip/hip_bf16.h>
#include <math.h>

#define EMBED 1024
#define LSEQ 4096
#define BATCH 2
#define ZD 128
#define CHUNKC 2048
#define NSTATE 16
#define DTR 64
#define XDBL_W 96   // DT_RANK + 2*DSTATE
#define NSEG 64
#define TSEG 64     // LSEQ / NSEG

typedef __attribute__((ext_vector_type(8))) short bf16x8;
typedef __attribute__((ext_vector_type(4))) float f32x4;

__device__ __forceinline__ float sigmoidf_(float x){ return 1.f/(1.f+__expf(-x)); }
__device__ __forceinline__ float siluf_(float x){ return x/(1.f+__expf(-x)); }
__device__ __forceinline__ __hip_bfloat16 tobf(float x){ return __float2bfloat16(x); }
__device__ __forceinline__ float frombf(__hip_bfloat16 x){ return __bfloat162float(x); }

__device__ __forceinline__ void gload_lds16(const void* g, void* l) {
  __builtin_amdgcn_global_load_lds(
      (const __attribute__((address_space(1))) unsigned int*)g,
      (__attribute__((address_space(3))) unsigned int*)l, 16, 0, 0);
}

// ---------------------------------------------------------------- f32 -> bf16 converts
__global__ __launch_bounds__(256) void cvt_k(const float* __restrict__ s,
                                             __hip_bfloat16* __restrict__ d, int n) {
  for (int i = (blockIdx.x*256 + threadIdx.x)*4; i < n; i += gridDim.x*256*4) {
    float4 v = *(const float4*)(s + i);
    d[i+0]=tobf(v.x); d[i+1]=tobf(v.y); d[i+2]=tobf(v.z); d[i+3]=tobf(v.w);
  }
}

__global__ __launch_bounds__(256) void cvt3_k(const float* __restrict__ s0, __hip_bfloat16* __restrict__ d0, int n0,
                                              const float* __restrict__ s1, __hip_bfloat16* __restrict__ d1, int n1,
                                              const float* __restrict__ s2, __hip_bfloat16* __restrict__ d2, int n2) {
  int i = (blockIdx.x*256 + threadIdx.x)*4;
  const float* s; __hip_bfloat16* d;
  if (i < n0) { s = s0 + i; d = d0 + i; }
  else if (i < n0+n1) { s = s1 + (i-n0); d = d1 + (i-n0); }
  else if (i < n0+n1+n2) { s = s2 + (i-n0-n1); d = d2 + (i-n0-n1); }
  else return;
  float4 v = *(const float4*)s;
  d[0]=tobf(v.x); d[1]=tobf(v.y); d[2]=tobf(v.z); d[3]=tobf(v.w);
}

// zero-padded convert (rows >= srcRows -> 0)
__global__ __launch_bounds__(256) void cvt_pad_k(const float* __restrict__ s,
                                                 __hip_bfloat16* __restrict__ d,
                                                 int srcRows, int cols, int dstRows) {
  int idx = blockIdx.x*256 + threadIdx.x;
  if (idx >= dstRows*cols) return;
  int r = idx / cols;
  d[idx] = tobf(r < srcRows ? s[idx] : 0.f);
}

// ---------------------------------------------------------------- rmsnorm (dual out: f32 + bf16)
__global__ __launch_bounds__(256) void rmsnorm_k(const float* __restrict__ x,
                                                 const float* __restrict__ w,
                                                 float* __restrict__ xn,
                                                 __hip_bfloat16* __restrict__ xnb) {
  size_t row = blockIdx.x;
  const float* px = x + row*EMBED;
  int tid = threadIdx.x;
  float4 xv = *(const float4*)(px + tid*4);
  float ss = xv.x*xv.x + xv.y*xv.y + xv.z*xv.z + xv.w*xv.w;
  #pragma unroll
  for (int off=32; off; off>>=1) ss += __shfl_down(ss, off, 64);
  __shared__ float red[4];
  if ((tid&63)==0) red[tid>>6]=ss;
  __syncthreads();
  float tot = red[0]+red[1]+red[2]+red[3];
  float scale = rsqrtf(tot*(1.f/EMBED) + 1e-5f);
  float4 wv = *(const float4*)(w + tid*4);
  float4 o;
  o.x=xv.x*scale*wv.x; o.y=xv.y*scale*wv.y; o.z=xv.z*scale*wv.z; o.w=xv.w*scale*wv.w;
  *(float4*)(xn + row*EMBED + tid*4) = o;
  __hip_bfloat16* pb = xnb + row*EMBED + tid*4;
  pb[0]=tobf(o.x); pb[1]=tobf(o.y); pb[2]=tobf(o.z); pb[3]=tobf(o.w);
}

// ---------------------------------------------------------------- gtab (Toeplitz rel-pos bias)
__global__ __launch_bounds__(256) void gtab_k(const float* __restrict__ alpha,
                                              const float* __restrict__ beta,
                                              float* __restrict__ gtab) {
  __shared__ float P[64], Q[64], F[64];
  int tid = threadIdx.x;
  if (tid < 64) {
    float a1=alpha[tid], a2=alpha[64+tid], b1=beta[tid], b2=beta[64+tid];
    P[tid]=a1*b1+a2*b2;
    Q[tid]=a2*b1-a1*b2;
    F[tid]=expf(-0.14391156831f*(float)tid); // ln(10000)/64
  }
  __syncthreads();
  int d = blockIdx.x*256 + tid;
  if (d < CHUNKC) {
    float s=0.f;
    for (int j=0;j<64;++j){
      float th = (float)d * F[j];
      float sn, cs;
      sincosf(th, &sn, &cs);
      s += P[j]*cs - Q[j]*sn;
    }
    gtab[d]=s;
  }
}

// ---------------------------------------------------------------- segment-parallel S6 scan
template<bool FINAL>
__global__ __launch_bounds__(256) void seg_scan_k(
    const float* __restrict__ xdbl,
    const float* __restrict__ dtv,
    const float* __restrict__ xn,
    const float* __restrict__ A_log,
    const float* __restrict__ D_p,
    const float* __restrict__ segInit,
    float* __restrict__ segP,
    float* __restrict__ segH,
    __hip_bfloat16* __restrict__ mx)
{
  int bx = blockIdx.x;
  int seg = bx >> 3;
  int grp = bx & 7;
  int b = grp >> 2;
  int d = (grp & 3)*256 + threadIdx.x;
  int ch = b*EMBED + d;
  int tid = threadIdx.x;
  int tbase = seg*TSEG;

  float A[NSTATE], h[NSTATE], P[NSTATE];
  #pragma unroll
  for (int n=0;n<NSTATE;++n){
    A[n] = -__expf(A_log[(size_t)d*NSTATE+n]);
    P[n] = 1.f;
  }
  if (FINAL) {
    const float* si = segInit + ((size_t)seg*2048 + ch)*NSTATE;
    #pragma unroll
    for (int n=0;n<NSTATE;++n) h[n] = si[n];
  } else {
    #pragma unroll
    for (int n=0;n<NSTATE;++n) h[n] = 0.f;
  }
  float Dp = FINAL ? D_p[d] : 0.f;

  __shared__ float BCb[8][32];
  const float* xd  = xdbl + ((size_t)b*LSEQ + tbase)*XDBL_W + DTR;
  const float* pdt = dtv + ((size_t)b*LSEQ + tbase)*EMBED + d;
  const float* pu  = xn  + ((size_t)b*LSEQ + tbase)*EMBED + d;
  __hip_bfloat16* pmx = mx + ((size_t)b*LSEQ + tbase)*EMBED + d;

  for (int t0=0; t0<TSEG; t0+=8) {
    __syncthreads();
    { int tt = tid>>5, jj = tid&31;
      BCb[tt][jj] = xd[(size_t)(t0+tt)*XDBL_W + jj]; }
    __syncthreads();
    #pragma unroll
    for (int tt=0; tt<8; ++tt) {
      int t = t0 + tt;
      float dtt = pdt[(size_t)t*EMBED];
      float ut  = pu[(size_t)t*EMBED];
      float du = dtt*ut;
      float y = 0.f;
      #pragma unroll
      for (int n=0;n<NSTATE;++n){
        float dA = __expf(dtt*A[n]);
        h[n] = dA*h[n] + du*BCb[tt][n];
        if (!FINAL) P[n] *= dA;
        if (FINAL)  y += h[n]*BCb[tt][16+n];
      }
      if (FINAL) pmx[(size_t)t*EMBED] = tobf(siluf_(y + ut*Dp));
    }
  }
  if (!FINAL) {
    float* pp = segP + ((size_t)seg*2048 + ch)*NSTATE;
    float* ph = segH + ((size_t)seg*2048 + ch)*NSTATE;
    #pragma unroll
    for (int n=0;n<NSTATE;n+=4){
      *(float4*)(pp+n) = make_float4(P[n],P[n+1],P[n+2],P[n+3]);
      *(float4*)(ph+n) = make_float4(h[n],h[n+1],h[n+2],h[n+3]);
    }
  }
}

__global__ __launch_bounds__(256) void seg_combine_k(const float* __restrict__ segP,
                                                     const float* __restrict__ segH,
                                                     float* __restrict__ segInit) {
  int idx = blockIdx.x*256 + threadIdx.x;
  float H = 0.f;
  for (int s=0; s<NSEG; ++s) {
    size_t o = (size_t)s*32768 + idx;
    float Pv = segP[o], hl = segH[o];
    segInit[o] = H;
    H = Pv*H + hl;
  }
}

// ---------------------------------------------------------------- row softmax (bf16 in, bf16 out), causal-aware
__global__ __launch_bounds__(256) void softmax_k(const __hip_bfloat16* __restrict__ S,
                                                 __hip_bfloat16* __restrict__ Sb) {
  size_t row = blockIdx.x;
  const __hip_bfloat16* p = S + row*CHUNKC;
  __hip_bfloat16* po = Sb + row*CHUNKC;
  int tid = threadIdx.x;
  int r = (int)(row & (CHUNKC-1));
  int nb = (r >> 8) + 1;
  float v[8];
  float m = -1e30f;
  #pragma unroll
  for (int i=0;i<8;++i){
    if (i < nb) {
      float t = frombf(p[tid + i*256]);
      v[i] = (i*256 + tid <= r) ? t : -1e30f;
    } else v[i] = -1e30f;
    m = fmaxf(m, v[i]);
  }
  #pragma unroll
  for (int off=32; off; off>>=1) m = fmaxf(m, __shfl_down(m, off, 64));
  __shared__ float red[4];
  if ((tid&63)==0) red[tid>>6]=m;
  __syncthreads();
  m = fmaxf(fmaxf(red[0],red[1]),fmaxf(red[2],red[3]));
  float s=0.f;
  #pragma unroll
  for (int i=0;i<8;++i){ v[i]=__expf(v[i]-m); s+=v[i]; }
  #pragma unroll
  for (int off=32; off; off>>=1) s += __shfl_down(s, off, 64);
  __syncthreads();
  if ((tid&63)==0) red[tid>>6]=s;
  __syncthreads();
  s = red[0]+red[1]+red[2]+red[3];
  float inv = 1.f/s;
  #pragma unroll
  for (int i=0;i<8;++i) po[tid + i*256] = tobf(v[i]*inv);
}

// ---------------------------------------------------------------- bf16 transpose V -> VT[c][n][k]
__global__ __launch_bounds__(256) void transpose_k(const unsigned short* __restrict__ vb,
                                                   unsigned short* __restrict__ VT) {
  __shared__ unsigned short t[64][68];
  int tid = threadIdx.x;
  int tr = tid>>4;
  int tc = (tid&15)*4;
  int c0 = blockIdx.x*64, r0 = blockIdx.y*64;
  #pragma unroll
  for (int it=0; it<4; ++it) {
    int r = it*16 + tr;
    ushort4 v = *(const ushort4*)(vb + (size_t)(r0+r)*EMBED + c0 + tc);
    t[r][tc+0]=v.x; t[r][tc+1]=v.y; t[r][tc+2]=v.z; t[r][tc+3]=v.w;
  }
  __syncthreads();
  int ch = r0 >> 11;
  int kb = r0 & 2047;
  #pragma unroll
  for (int it=0; it<4; ++it) {
    int nl = it*16 + tr;
    ushort4 o;
    o.x = t[tc+0][nl]; o.y = t[tc+1][nl]; o.z = t[tc+2][nl]; o.w = t[tc+3][nl];
    *(ushort4*)(VT + ((size_t)ch*EMBED + c0 + nl)*CHUNKC + kb + tc) = o;
  }
}

// ---------------------------------------------------------------- bf16 MFMA GEMM
// 128x128 tile, BK=64, double-buffered LDS, XOR-swizzled staging/reads,
// counted-vmcnt pipeline, bijective XCD swizzle, __launch_bounds__(256,3)
// -> target 3 resident blocks/CU (m97's overlap mechanism).
// EPI: 0 silu+bias->bf16; 1 base-split; 2 QK bias+mask->bf16 lower-tri;
//      3 PV*r->bf16 (TRIK); 4 final gate->f32 out; 5 xdbl dual; 6 dt softplus
struct MEp {
  const float* bias; const float* gtab; const float* gamma; const float* beta2;
  __hip_bfloat16* ug; __hip_bfloat16* qo; __hip_bfloat16* ko; __hip_bfloat16* ro; __hip_bfloat16* hxo;
  const __hip_bfloat16* rb; const __hip_bfloat16* hxb; const __hip_bfloat16* ub;
  const float* resid; float* outp;
  __hip_bfloat16* Cb; int ldc;
  float* f32o; __hip_bfloat16* bf16o;
};

__device__ __forceinline__ void xcd_swz(int& bx, int& by) {
  const int gx = gridDim.x;
  const int nwg = gx*gridDim.y;
  const int lin = by*gx + bx;
  const int qq = nwg >> 3, rr = nwg & 7;
  const int xcd = lin & 7, pos = lin >> 3;
  const int base = (xcd < rr) ? xcd*(qq+1) : rr*(qq+1) + (xcd-rr)*qq;
  const int lg = base + pos;
  bx = lg % gx; by = lg / gx;
}

#define MBM 128
#define MBK 64

template<int EPI, bool TRIK, bool SWZ>
__global__ __launch_bounds__(256, 3) void mgemm_k(
    const __hip_bfloat16* __restrict__ A, int lda, long long sAz,
    const __hip_bfloat16* __restrict__ B, int ldb, long long sBz,
    int K, MEp ep)
{
  __shared__ __attribute__((aligned(16))) short As[2][MBM*MBK];
  __shared__ __attribute__((aligned(16))) short Bs[2][MBM*MBK];
  const int tid = threadIdx.x;
  const int wv = tid>>6, lane = tid&63;
  const int z = blockIdx.z;
  A += (size_t)z * sAz;
  B += (size_t)z * sBz;
  int bx = blockIdx.x, by = blockIdx.y;
  if constexpr (SWZ) xcd_swz(bx, by);
  const int m0 = by*MBM, n0 = bx*MBM;
  if constexpr (EPI==2) { if (n0 > m0 + (MBM-1)) return; }
  const int r8 = lane>>3, g8 = lane&7;
  const int csrc = g8 ^ r8;
  const int wr = wv>>1, wc = wv&1;
  const int fr = lane&15, qv = lane>>4;
  const int x7 = fr & 7;

  int Ktot = K;
  if constexpr (TRIK) { int km = m0 + MBM; Ktot = km < K ? km : K; }
  const int nt = Ktot / MBK;

  f32x4 acc[4][4] = {};

  const __hip_bfloat16* Ag = A + (size_t)(m0 + wv*32 + r8)*lda + csrc*8;
  const __hip_bfloat16* Bg = B + (size_t)(n0 + wv*32 + r8)*ldb + csrc*8;

  auto stage = [&](int buf, int t){
    const int k0 = t*MBK;
    short* Al = &As[buf][wv*32*MBK];
    short* Bl = &Bs[buf][wv*32*MBK];
    #pragma unroll
    for (int j=0;j<4;++j)
      gload_lds16(Ag + (size_t)(j*8)*lda + k0, Al + j*8*MBK);
    #pragma unroll
    for (int j=0;j<4;++j)
      gload_lds16(Bg + (size_t)(j*8)*ldb + k0, Bl + j*8*MBK);
  };

  // prologue: fill both buffers, wait only buf0 (counted)
  stage(0, 0);
  if (nt > 1) {
    stage(1, 1);
    asm volatile("s_waitcnt vmcnt(8)" ::: "memory");
  } else {
    asm volatile("s_waitcnt vmcnt(0)" ::: "memory");
  }
  __builtin_amdgcn_sched_barrier(0);
  __builtin_amdgcn_s_barrier();

  for (int t=0; t<nt; ++t) {
    const int cur = t & 1;
    const short* Ab = &As[cur][0];
    const short* Bb = &Bs[cur][0];
    #pragma unroll
    for (int kk=0; kk<2; ++kk) {
      const int pos8 = ((kk*4 + qv) ^ x7) * 8;
      bf16x8 af[4], bfr[4];
      #pragma unroll
      for (int mi=0;mi<4;++mi)
        af[mi] = *(const bf16x8*)&Ab[(wr*64 + mi*16 + fr)*MBK + pos8];
      #pragma unroll
      for (int ni=0;ni<4;++ni)
        bfr[ni] = *(const bf16x8*)&Bb[(wc*64 + ni*16 + fr)*MBK + pos8];
      #pragma unroll
      for (int mi=0;mi<4;++mi)
        #pragma unroll
        for (int ni=0;ni<4;++ni)
          acc[mi][ni] = __builtin_amdgcn_mfma_f32_16x16x32_bf16(af[mi], bfr[ni], acc[mi][ni], 0,0,0);
    }
    if (t+1 >= nt) break;
    __builtin_amdgcn_sched_barrier(0);
    __builtin_amdgcn_s_barrier();            // all waves done reading buf[cur]
    if (t+2 < nt) {
      stage(cur, t+2);
      asm volatile("s_waitcnt vmcnt(8)" ::: "memory");   // t+1's loads done; t+2's in flight
    } else {
      asm volatile("s_waitcnt vmcnt(0)" ::: "memory");
    }
    __builtin_amdgcn_sched_barrier(0);
    __builtin_amdgcn_s_barrier();            // buf[cur^1] ready on all waves
  }

  const int vr = (lane>>4)*4;
  #pragma unroll
  for (int mi=0;mi<4;++mi) {
    #pragma unroll
    for (int v=0; v<4; ++v) {
      const int row = m0 + wr*64 + mi*16 + vr + v;
      #pragma unroll
      for (int ni=0;ni<4;++ni) {
        const int col = n0 + wc*64 + ni*16 + fr;
        float val = acc[mi][ni][v];
        if constexpr (EPI==0) {
          ep.Cb[(size_t)row*ep.ldc + col] = tobf(siluf_(val + ep.bias[col]));
        } else if constexpr (EPI==1) {
          val += ep.bias[col];
          if (col < 1024) {
            ep.ug[(size_t)row*EMBED + col] = tobf(sigmoidf_(val));
          } else if (col < 1152) {
            int jj = col - 1024;
            float zz = siluf_(val);
            ep.qo[(size_t)row*ZD + jj] = tobf((zz*ep.gamma[jj] + ep.beta2[jj]) * 0.08838834764831845f);
            ep.ko[(size_t)row*ZD + jj] = tobf(zz*ep.gamma[128+jj] + ep.beta2[128+jj]);
          } else if (col < 2176) {
            ep.ro[(size_t)row*EMBED + (col-1152)] = tobf(siluf_(val));
          } else {
            ep.hxo[(size_t)row*EMBED + (col-2176)] = tobf(val);
          }
        } else if constexpr (EPI==2) {
          __hip_bfloat16* Sp = ep.Cb + (size_t)z*CHUNKC*CHUNKC;
          if (col <= row) Sp[(size_t)row*CHUNKC + col] = tobf(val + ep.gtab[row-col]);
        } else if constexpr (EPI==3) {
          size_t gr = (size_t)z*CHUNKC + row;
          ep.Cb[gr*EMBED + col] = tobf(val * frombf(ep.rb[gr*EMBED + col]));
        } else if constexpr (EPI==4) {
          float zz = val + ep.bias[col] + frombf(ep.hxb[(size_t)row*EMBED + col]);
          float hh = siluf_(zz);
          float res = ep.resid[(size_t)row*EMBED + col];
          ep.outp[(size_t)row*EMBED + col] = res + frombf(ep.ub[(size_t)row*EMBED + col])*(hh-res);
        } else if constexpr (EPI==5) {
          if (col < XDBL_W) ep.f32o[(size_t)row*XDBL_W + col] = val;
          if (col < DTR)    ep.bf16o[(size_t)row*DTR + col] = tobf(val);
        } else {
          float zv = val + ep.bias[col];
          ep.f32o[(size_t)row*EMBED + col] = (zv > 15.f) ? zv : log1pf(__expf(zv));
        }
      }
    }
  }
}

// ---------------------------------------------------------------- launch
extern "C" void kernel_launch(void* const* d_in, const int* in_sizes, int n_in,
                              void* d_out, int out_size, void* d_ws, size_t ws_size,
                              hipStream_t stream) {
  const float* x       = (const float*)d_in[0];
  const float* norm_w  = (const float*)d_in[1];
  const float* v_w     = (const float*)d_in[2];
  const float* v_b     = (const float*)d_in[3];
  const float* mx_w    = (const float*)d_in[4];
  const float* mx_b    = (const float*)d_in[5];
  const float* h_w     = (const float*)d_in[6];
  const float* h_b     = (const float*)d_in[7];
  const float* gamma   = (const float*)d_in[8];
  const float* beta    = (const float*)d_in[9];
  const float* alpha_rb= (const float*)d_in[10];
  const float* beta_rb = (const float*)d_in[11];
  const float* xproj_w = (const float*)d_in[12];
  const float* dt_w    = (const float*)d_in[13];
  const float* dt_b    = (const float*)d_in[14];
  const float* A_log   = (const float*)d_in[15];
  const float* D_p     = (const float*)d_in[16];
  float* out = (float*)d_out;

  float* ws = (float*)d_ws;
  size_t off = 0;
  auto alloc = [&](size_t n){ float* p = ws + off; off += n; return p; };
  const size_t BL2 = (size_t)BATCH*LSEQ; // 8192

  float* xn      = alloc(BL2*EMBED);        // f32; later aliased by Sb
  float* scratch = alloc((size_t)2*CHUNKC*CHUNKC*2); // dtb+seg*, then S(bf16)
  float* xdbl    = alloc(BL2*XDBL_W);
  float* gtab    = alloc(CHUNKC);
  auto balloc = [&](size_t nbf){ __hip_bfloat16* p = (__hip_bfloat16*)(ws + off); off += (nbf+1)/2; return p; };
  __hip_bfloat16* xnb   = balloc(BL2*EMBED);   // later reused as VT
  __hip_bfloat16* vbufb = balloc(BL2*EMBED);
  __hip_bfloat16* mxb   = balloc(BL2*EMBED);
  __hip_bfloat16* qb    = balloc(BL2*ZD);
  __hip_bfloat16* kb    = balloc(BL2*ZD);
  __hip_bfloat16* ugb   = balloc(BL2*EMBED);
  __hip_bfloat16* rbb   = balloc(BL2*EMBED);
  __hip_bfloat16* hxbb  = balloc(BL2*EMBED);
  __hip_bfloat16* hrb   = balloc(BL2*EMBED);
  __hip_bfloat16* xdblb = balloc(BL2*DTR);
  __hip_bfloat16* vwb   = balloc((size_t)EMBED*EMBED);
  __hip_bfloat16* mxwb  = balloc((size_t)3200*EMBED);
  __hip_bfloat16* hwb   = balloc((size_t)EMBED*EMBED);
  __hip_bfloat16* xpwb  = balloc((size_t)128*EMBED);   // xproj_w padded 96->128 rows
  __hip_bfloat16* dtwb  = balloc((size_t)EMBED*DTR);

  float* dtb     = scratch;
  float* segP    = scratch + BL2*EMBED;
  float* segH    = segP + (size_t)NSEG*2048*NSTATE;
  float* segInit = segH + (size_t)NSEG*2048*NSTATE;
  __hip_bfloat16* S  = (__hip_bfloat16*)scratch;  // after scan (bf16 4*2048*2048)
  __hip_bfloat16* Sb = (__hip_bfloat16*)xn;       // after scan
  __hip_bfloat16* VT = xnb;                       // after v + xdbl GEMMs

  // 0. weight conversions + bias table
  cvt3_k<<<(2*EMBED*EMBED + EMBED*DTR + 1023)/1024, 256, 0, stream>>>(
      v_w, vwb, EMBED*EMBED, h_w, hwb, EMBED*EMBED, dt_w, dtwb, EMBED*DTR);
  cvt_k<<<512, 256, 0, stream>>>(mx_w, mxwb, 3200*EMBED);
  cvt_pad_k<<<(128*EMBED+255)/256, 256, 0, stream>>>(xproj_w, xpwb, XDBL_W, EMBED, 128);
  gtab_k<<<CHUNKC/256, 256, 0, stream>>>(alpha_rb, beta_rb, gtab);

  // 1. rmsnorm
  rmsnorm_k<<<(int)BL2, 256, 0, stream>>>(x, norm_w, xn, xnb);

  MEp ep;

  // 2. v = silu(xn @ v_w^T + v_b)  [bf16]
  ep = {}; ep.bias = v_b; ep.Cb = vbufb; ep.ldc = EMBED;
  mgemm_k<0,false,true><<<dim3(EMBED/MBM, BL2/MBM), 256, 0, stream>>>(
      xnb, EMBED, 0, vwb, EMBED, 0, EMBED, ep);

  // 3. xdbl = xn @ xproj_w^T  (f32 96 cols + bf16 first 64)
  ep = {}; ep.f32o = xdbl; ep.bf16o = xdblb;
  mgemm_k<5,false,false><<<dim3(1, BL2/MBM), 256, 0, stream>>>(
      xnb, EMBED, 0, xpwb, EMBED, 0, EMBED, ep);

  // 4. dt = softplus(xdbl[:, :64] @ dt_w^T + dt_b)  (f32)
  ep = {}; ep.bias = dt_b; ep.f32o = dtb;
  mgemm_k<6,false,true><<<dim3(EMBED/MBM, BL2/MBM), 256, 0, stream>>>(
      xdblb, DTR, 0, dtwb, DTR, 0, DTR, ep);

  // 2b. transpose V per chunk (xnb dead now)
  transpose_k<<<dim3(EMBED/64, BL2/64), 256, 0, stream>>>(
      (const unsigned short*)vbufb, (unsigned short*)VT);

  // 5. segment-parallel scan -> mxb
  seg_scan_k<false><<<NSEG*8, 256, 0, stream>>>(xdbl, dtb, xn, A_log, D_p,
                                                nullptr, segP, segH, nullptr);
  seg_combine_k<<<128, 256, 0, stream>>>(segP, segH, segInit);
  seg_scan_k<true><<<NSEG*8, 256, 0, stream>>>(xdbl, dtb, xn, A_log, D_p,
                                               segInit, nullptr, nullptr, mxb);

  // 6. base = mx @ mx_w^T + mx_b, split epilogue
  ep = {}; ep.bias = mx_b; ep.gamma = gamma; ep.beta2 = beta;
  ep.ug = ugb; ep.qo = qb; ep.ko = kb; ep.ro = rbb; ep.hxo = hxbb;
  mgemm_k<1,false,true><<<dim3(3200/MBM, BL2/MBM), 256, 0, stream>>>(
      mxb, EMBED, 0, mxwb, EMBED, 0, EMBED, ep);

  // 7. QK^T + bias + mask -> bf16 S (upper-triangle tiles + stores skipped)
  ep = {}; ep.gtab = gtab; ep.Cb = S;
  mgemm_k<2,false,true><<<dim3(CHUNKC/MBM, CHUNKC/MBM, 4), 256, 0, stream>>>(
      qb, ZD, (long long)CHUNKC*ZD, kb, ZD, (long long)CHUNKC*ZD, ZD, ep);

  // 8. softmax (causal-aware reads, bf16 in/out)
  softmax_k<<<4*CHUNKC, 256, 0, stream>>>(S, Sb);

  // 9. P@V, K clipped to diagonal, fused *r -> bf16
  ep = {}; ep.rb = rbb; ep.Cb = hrb;
  mgemm_k<3,true,true><<<dim3(EMBED/MBM, CHUNKC/MBM, 4), 256, 0, stream>>>(
      Sb, CHUNKC, (long long)CHUNKC*CHUNKC, VT, CHUNKC, (long long)EMBED*CHUNKC, CHUNKC, ep);

  // 10. final: h = silu(hx + (h*r) @ h_w^T + h_b); out = x + u*(h-x)
  ep = {}; ep.bias = h_b; ep.hxb = hxbb; ep.ub = ugb; ep.resid = x; ep.outp = out;
  mgemm_k<4,false,true><<<dim3(EMBED/MBM, BL2/MBM), 256, 0, stream>>>(
      hrb, EMBED, 0, hwb, EMBED, 0, EMBED, ep);
}

// Round 10
// 502.920 us; speedup vs baseline: 1.0928x; 1.0114x over previous
//
#include <hip/hip_runtime.h>
#include <hip/hip_bf16.h>
#include <math.h>

#define EMBED 1024
#define LSEQ 4096
#define BATCH 2
#define ZD 128
#define CHUNKC 2048
#define NSTATE 16
#define DTR 64
#define XDBL_W 96   // DT_RANK + 2*DSTATE
#define NSEG 64
#define TSEG 64     // LSEQ / NSEG

typedef __attribute__((ext_vector_type(8))) short bf16x8;
typedef __attribute__((ext_vector_type(4))) float f32x4;

__device__ __forceinline__ float sigmoidf_(float x){ return 1.f/(1.f+__expf(-x)); }
__device__ __forceinline__ float siluf_(float x){ return x/(1.f+__expf(-x)); }
__device__ __forceinline__ __hip_bfloat16 tobf(float x){ return __float2bfloat16(x); }
__device__ __forceinline__ float frombf(__hip_bfloat16 x){ return __bfloat162float(x); }

__device__ __forceinline__ void gload_lds16(const void* g, void* l) {
  __builtin_amdgcn_global_load_lds(
      (const __attribute__((address_space(1))) unsigned int*)g,
      (__attribute__((address_space(3))) unsigned int*)l, 16, 0, 0);
}

// ---------------------------------------------------------------- unified prep:
// block ranges: [0,1024) v_w->wcat ; [1024,1120) xproj->wcat+1M ; [1120,1152) zero-pad ;
// [1152,2176) h_w->hwb ; [2176,2240) dt_w->dtwb ; [2240,5440) mx_w->mxwb ; [5440,5448) gtab
__global__ __launch_bounds__(256) void prep_k(
    const float* __restrict__ v_w, const float* __restrict__ xproj_w,
    const float* __restrict__ h_w, const float* __restrict__ dt_w,
    const float* __restrict__ mx_w,
    const float* __restrict__ alpha, const float* __restrict__ beta,
    __hip_bfloat16* __restrict__ wcat, __hip_bfloat16* __restrict__ hwb,
    __hip_bfloat16* __restrict__ dtwb, __hip_bfloat16* __restrict__ mxwb,
    float* __restrict__ gtab)
{
  int b = blockIdx.x, tid = threadIdx.x;
  if (b < 5440) {
    const float* s; __hip_bfloat16* d; int idx;
    if (b < 1024)      { idx = (b*256+tid)*4;        s = v_w + idx;      d = wcat + idx; }
    else if (b < 1120) { idx = ((b-1024)*256+tid)*4; s = xproj_w + idx;  d = wcat + (1<<20) + idx; }
    else if (b < 1152) { idx = ((b-1120)*256+tid)*4; s = nullptr;        d = wcat + (1<<20) + 96*1024 + idx; }
    else if (b < 2176) { idx = ((b-1152)*256+tid)*4; s = h_w + idx;      d = hwb + idx; }
    else if (b < 2240) { idx = ((b-2176)*256+tid)*4; s = dt_w + idx;     d = dtwb + idx; }
    else               { idx = ((b-2240)*256+tid)*4; s = mx_w + idx;     d = mxwb + idx; }
    if (s) {
      float4 v = *(const float4*)s;
      d[0]=tobf(v.x); d[1]=tobf(v.y); d[2]=tobf(v.z); d[3]=tobf(v.w);
    } else {
      d[0]=tobf(0.f); d[1]=tobf(0.f); d[2]=tobf(0.f); d[3]=tobf(0.f);
    }
    return;
  }
  // gtab
  __shared__ float P[64], Q[64], F[64];
  if (tid < 64) {
    float a1=alpha[tid], a2=alpha[64+tid], b1=beta[tid], b2=beta[64+tid];
    P[tid]=a1*b1+a2*b2;
    Q[tid]=a2*b1-a1*b2;
    F[tid]=expf(-0.14391156831f*(float)tid); // ln(10000)/64
  }
  __syncthreads();
  int d = (b-5440)*256 + tid;
  if (d < CHUNKC) {
    float s=0.f;
    for (int j=0;j<64;++j){
      float th = (float)d * F[j];
      float sn, cs;
      sincosf(th, &sn, &cs);
      s += P[j]*cs - Q[j]*sn;
    }
    gtab[d]=s;
  }
}

// ---------------------------------------------------------------- rmsnorm (dual out: f32 + bf16)
__global__ __launch_bounds__(256) void rmsnorm_k(const float* __restrict__ x,
                                                 const float* __restrict__ w,
                                                 float* __restrict__ xn,
                                                 __hip_bfloat16* __restrict__ xnb) {
  size_t row = blockIdx.x;
  const float* px = x + row*EMBED;
  int tid = threadIdx.x;
  float4 xv = *(const float4*)(px + tid*4);
  float ss = xv.x*xv.x + xv.y*xv.y + xv.z*xv.z + xv.w*xv.w;
  #pragma unroll
  for (int off=32; off; off>>=1) ss += __shfl_down(ss, off, 64);
  __shared__ float red[4];
  if ((tid&63)==0) red[tid>>6]=ss;
  __syncthreads();
  float tot = red[0]+red[1]+red[2]+red[3];
  float scale = rsqrtf(tot*(1.f/EMBED) + 1e-5f);
  float4 wv = *(const float4*)(w + tid*4);
  float4 o;
  o.x=xv.x*scale*wv.x; o.y=xv.y*scale*wv.y; o.z=xv.z*scale*wv.z; o.w=xv.w*scale*wv.w;
  *(float4*)(xn + row*EMBED + tid*4) = o;
  __hip_bfloat16* pb = xnb + row*EMBED + tid*4;
  pb[0]=tobf(o.x); pb[1]=tobf(o.y); pb[2]=tobf(o.z); pb[3]=tobf(o.w);
}

// ---------------------------------------------------------------- segment-parallel S6 scan
template<bool FINAL>
__global__ __launch_bounds__(256) void seg_scan_k(
    const float* __restrict__ xdbl,
    const float* __restrict__ dtv,
    const float* __restrict__ xn,
    const float* __restrict__ A_log,
    const float* __restrict__ D_p,
    const float* __restrict__ segInit,
    float* __restrict__ segP,
    float* __restrict__ segH,
    __hip_bfloat16* __restrict__ mx)
{
  int bx = blockIdx.x;
  int seg = bx >> 3;
  int grp = bx & 7;
  int b = grp >> 2;
  int d = (grp & 3)*256 + threadIdx.x;
  int ch = b*EMBED + d;
  int tid = threadIdx.x;
  int tbase = seg*TSEG;

  float A[NSTATE], h[NSTATE], P[NSTATE];
  #pragma unroll
  for (int n=0;n<NSTATE;++n){
    A[n] = -__expf(A_log[(size_t)d*NSTATE+n]);
    P[n] = 1.f;
  }
  if (FINAL) {
    const float* si = segInit + ((size_t)seg*2048 + ch)*NSTATE;
    #pragma unroll
    for (int n=0;n<NSTATE;++n) h[n] = si[n];
  } else {
    #pragma unroll
    for (int n=0;n<NSTATE;++n) h[n] = 0.f;
  }
  float Dp = FINAL ? D_p[d] : 0.f;

  __shared__ float BCb[8][32];
  const float* xd  = xdbl + ((size_t)b*LSEQ + tbase)*XDBL_W + DTR;
  const float* pdt = dtv + ((size_t)b*LSEQ + tbase)*EMBED + d;
  const float* pu  = xn  + ((size_t)b*LSEQ + tbase)*EMBED + d;
  __hip_bfloat16* pmx = mx + ((size_t)b*LSEQ + tbase)*EMBED + d;

  for (int t0=0; t0<TSEG; t0+=8) {
    __syncthreads();
    { int tt = tid>>5, jj = tid&31;
      BCb[tt][jj] = xd[(size_t)(t0+tt)*XDBL_W + jj]; }
    __syncthreads();
    #pragma unroll
    for (int tt=0; tt<8; ++tt) {
      int t = t0 + tt;
      float dtt = pdt[(size_t)t*EMBED];
      float ut  = pu[(size_t)t*EMBED];
      float du = dtt*ut;
      float y = 0.f;
      #pragma unroll
      for (int n=0;n<NSTATE;++n){
        float dA = __expf(dtt*A[n]);
        h[n] = dA*h[n] + du*BCb[tt][n];
        if (!FINAL) P[n] *= dA;
        if (FINAL)  y += h[n]*BCb[tt][16+n];
      }
      if (FINAL) pmx[(size_t)t*EMBED] = tobf(siluf_(y + ut*Dp));
    }
  }
  if (!FINAL) {
    float* pp = segP + ((size_t)seg*2048 + ch)*NSTATE;
    float* ph = segH + ((size_t)seg*2048 + ch)*NSTATE;
    #pragma unroll
    for (int n=0;n<NSTATE;n+=4){
      *(float4*)(pp+n) = make_float4(P[n],P[n+1],P[n+2],P[n+3]);
      *(float4*)(ph+n) = make_float4(h[n],h[n+1],h[n+2],h[n+3]);
    }
  }
}

__global__ __launch_bounds__(256) void seg_combine_k(const float* __restrict__ segP,
                                                     const float* __restrict__ segH,
                                                     float* __restrict__ segInit) {
  int idx = blockIdx.x*256 + threadIdx.x;
  float H = 0.f;
  for (int s=0; s<NSEG; ++s) {
    size_t o = (size_t)s*32768 + idx;
    float Pv = segP[o], hl = segH[o];
    segInit[o] = H;
    H = Pv*H + hl;
  }
}

// ---------------------------------------------------------------- row softmax (bf16 in, bf16 out)
// causal-aware reads; writes clipped to kcl = 128*ceil((r+1)/128) (all PV reads beyond are skipped)
__global__ __launch_bounds__(256) void softmax_k(const __hip_bfloat16* __restrict__ S,
                                                 __hip_bfloat16* __restrict__ Sb) {
  size_t row = blockIdx.x;
  const __hip_bfloat16* p = S + row*CHUNKC;
  __hip_bfloat16* po = Sb + row*CHUNKC;
  int tid = threadIdx.x;
  int r = (int)(row & (CHUNKC-1));
  int nb = (r >> 8) + 1;
  int kcl = ((r >> 7) + 1) << 7;
  float v[8];
  float m = -1e30f;
  #pragma unroll
  for (int i=0;i<8;++i){
    if (i < nb) {
      float t = frombf(p[tid + i*256]);
      v[i] = (i*256 + tid <= r) ? t : -1e30f;
    } else v[i] = -1e30f;
    m = fmaxf(m, v[i]);
  }
  #pragma unroll
  for (int off=32; off; off>>=1) m = fmaxf(m, __shfl_down(m, off, 64));
  __shared__ float red[4];
  if ((tid&63)==0) red[tid>>6]=m;
  __syncthreads();
  m = fmaxf(fmaxf(red[0],red[1]),fmaxf(red[2],red[3]));
  float s=0.f;
  #pragma unroll
  for (int i=0;i<8;++i){ v[i]=__expf(v[i]-m); s+=v[i]; }
  #pragma unroll
  for (int off=32; off; off>>=1) s += __shfl_down(s, off, 64);
  __syncthreads();
  if ((tid&63)==0) red[tid>>6]=s;
  __syncthreads();
  s = red[0]+red[1]+red[2]+red[3];
  float inv = 1.f/s;
  #pragma unroll
  for (int i=0;i<8;++i){
    int c = tid + i*256;
    if (c < kcl) po[c] = tobf(v[i]*inv);
  }
}

// ---------------------------------------------------------------- bf16 transpose V -> VT[c][n][k]
__global__ __launch_bounds__(256) void transpose_k(const unsigned short* __restrict__ vb,
                                                   unsigned short* __restrict__ VT) {
  __shared__ unsigned short t[64][68];
  int tid = threadIdx.x;
  int tr = tid>>4;
  int tc = (tid&15)*4;
  int c0 = blockIdx.x*64, r0 = blockIdx.y*64;
  #pragma unroll
  for (int it=0; it<4; ++it) {
    int r = it*16 + tr;
    ushort4 v = *(const ushort4*)(vb + (size_t)(r0+r)*EMBED + c0 + tc);
    t[r][tc+0]=v.x; t[r][tc+1]=v.y; t[r][tc+2]=v.z; t[r][tc+3]=v.w;
  }
  __syncthreads();
  int ch = r0 >> 11;
  int kb = r0 & 2047;
  #pragma unroll
  for (int it=0; it<4; ++it) {
    int nl = it*16 + tr;
    ushort4 o;
    o.x = t[tc+0][nl]; o.y = t[tc+1][nl]; o.z = t[tc+2][nl]; o.w = t[tc+3][nl];
    *(ushort4*)(VT + ((size_t)ch*EMBED + c0 + nl)*CHUNKC + kb + tc) = o;
  }
}

// ---------------------------------------------------------------- bf16 MFMA GEMM
// 128x128 tile, BK=64, double-buffered LDS, XOR-swizzled staging/reads,
// counted-vmcnt pipeline, bijective XCD swizzle.
// EPI: 1 base-split; 2 QK bias+mask->bf16 lower-tri; 3 PV*r->bf16 (TRIK);
//      4 final gate->f32; 6 dt softplus->f32; 7 v+xdbl merged
struct MEp {
  const float* bias; const float* gtab; const float* gamma; const float* beta2;
  __hip_bfloat16* ug; __hip_bfloat16* qo; __hip_bfloat16* ko; __hip_bfloat16* ro; __hip_bfloat16* hxo;
  const __hip_bfloat16* rb; const __hip_bfloat16* hxb; const __hip_bfloat16* ub;
  const float* resid; float* outp;
  __hip_bfloat16* Cb; int ldc;
  float* f32o; __hip_bfloat16* bf16o;
};

__device__ __forceinline__ void xcd_swz(int& bx, int& by) {
  const int gx = gridDim.x;
  const int nwg = gx*gridDim.y;
  const int lin = by*gx + bx;
  const int qq = nwg >> 3, rr = nwg & 7;
  const int xcd = lin & 7, pos = lin >> 3;
  const int base = (xcd < rr) ? xcd*(qq+1) : rr*(qq+1) + (xcd-rr)*qq;
  const int lg = base + pos;
  bx = lg % gx; by = lg / gx;
}

#define MBM 128
#define MBK 64

template<int EPI, bool TRIK, bool SWZ>
__global__ __launch_bounds__(256, 3) void mgemm_k(
    const __hip_bfloat16* __restrict__ A, int lda, long long sAz,
    const __hip_bfloat16* __restrict__ B, int ldb, long long sBz,
    int K, MEp ep)
{
  __shared__ __attribute__((aligned(16))) short As[2][MBM*MBK];
  __shared__ __attribute__((aligned(16))) short Bs[2][MBM*MBK];
  const int tid = threadIdx.x;
  const int wv = tid>>6, lane = tid&63;
  const int z = blockIdx.z;
  A += (size_t)z * sAz;
  B += (size_t)z * sBz;
  int bx = blockIdx.x, by = blockIdx.y;
  if constexpr (SWZ) xcd_swz(bx, by);
  const int m0 = by*MBM, n0 = bx*MBM;
  if constexpr (EPI==2) { if (n0 > m0 + (MBM-1)) return; }
  const int r8 = lane>>3, g8 = lane&7;
  const int csrc = g8 ^ r8;
  const int wr = wv>>1, wc = wv&1;
  const int fr = lane&15, qv = lane>>4;
  const int x7 = fr & 7;

  int Ktot = K;
  if constexpr (TRIK) { int km = m0 + MBM; Ktot = km < K ? km : K; }
  const int nt = Ktot / MBK;

  f32x4 acc[4][4] = {};

  const __hip_bfloat16* Ag = A + (size_t)(m0 + wv*32 + r8)*lda + csrc*8;
  const __hip_bfloat16* Bg = B + (size_t)(n0 + wv*32 + r8)*ldb + csrc*8;

  auto stage = [&](int buf, int t){
    const int k0 = t*MBK;
    short* Al = &As[buf][wv*32*MBK];
    short* Bl = &Bs[buf][wv*32*MBK];
    #pragma unroll
    for (int j=0;j<4;++j)
      gload_lds16(Ag + (size_t)(j*8)*lda + k0, Al + j*8*MBK);
    #pragma unroll
    for (int j=0;j<4;++j)
      gload_lds16(Bg + (size_t)(j*8)*ldb + k0, Bl + j*8*MBK);
  };

  // prologue: fill both buffers, wait only buf0 (counted)
  stage(0, 0);
  if (nt > 1) {
    stage(1, 1);
    asm volatile("s_waitcnt vmcnt(8)" ::: "memory");
  } else {
    asm volatile("s_waitcnt vmcnt(0)" ::: "memory");
  }
  __builtin_amdgcn_sched_barrier(0);
  __builtin_amdgcn_s_barrier();

  for (int t=0; t<nt; ++t) {
    const int cur = t & 1;
    const short* Ab = &As[cur][0];
    const short* Bb = &Bs[cur][0];
    #pragma unroll
    for (int kk=0; kk<2; ++kk) {
      const int pos8 = ((kk*4 + qv) ^ x7) * 8;
      bf16x8 af[4], bfr[4];
      #pragma unroll
      for (int mi=0;mi<4;++mi)
        af[mi] = *(const bf16x8*)&Ab[(wr*64 + mi*16 + fr)*MBK + pos8];
      #pragma unroll
      for (int ni=0;ni<4;++ni)
        bfr[ni] = *(const bf16x8*)&Bb[(wc*64 + ni*16 + fr)*MBK + pos8];
      #pragma unroll
      for (int mi=0;mi<4;++mi)
        #pragma unroll
        for (int ni=0;ni<4;++ni)
          acc[mi][ni] = __builtin_amdgcn_mfma_f32_16x16x32_bf16(af[mi], bfr[ni], acc[mi][ni], 0,0,0);
    }
    if (t+1 >= nt) break;
    __builtin_amdgcn_sched_barrier(0);
    __builtin_amdgcn_s_barrier();            // all waves done reading buf[cur]
    if (t+2 < nt) {
      stage(cur, t+2);
      asm volatile("s_waitcnt vmcnt(8)" ::: "memory");   // t+1's loads done; t+2's in flight
    } else {
      asm volatile("s_waitcnt vmcnt(0)" ::: "memory");
    }
    __builtin_amdgcn_sched_barrier(0);
    __builtin_amdgcn_s_barrier();            // buf[cur^1] ready on all waves
  }

  const int vr = (lane>>4)*4;
  #pragma unroll
  for (int mi=0;mi<4;++mi) {
    #pragma unroll
    for (int v=0; v<4; ++v) {
      const int row = m0 + wr*64 + mi*16 + vr + v;
      #pragma unroll
      for (int ni=0;ni<4;++ni) {
        const int col = n0 + wc*64 + ni*16 + fr;
        float val = acc[mi][ni][v];
        if constexpr (EPI==1) {
          val += ep.bias[col];
          if (col < 1024) {
            ep.ug[(size_t)row*EMBED + col] = tobf(sigmoidf_(val));
          } else if (col < 1152) {
            int jj = col - 1024;
            float zz = siluf_(val);
            ep.qo[(size_t)row*ZD + jj] = tobf((zz*ep.gamma[jj] + ep.beta2[jj]) * 0.08838834764831845f);
            ep.ko[(size_t)row*ZD + jj] = tobf(zz*ep.gamma[128+jj] + ep.beta2[128+jj]);
          } else if (col < 2176) {
            ep.ro[(size_t)row*EMBED + (col-1152)] = tobf(siluf_(val));
          } else {
            ep.hxo[(size_t)row*EMBED + (col-2176)] = tobf(val);
          }
        } else if constexpr (EPI==2) {
          __hip_bfloat16* Sp = ep.Cb + (size_t)z*CHUNKC*CHUNKC;
          if (col <= row) Sp[(size_t)row*CHUNKC + col] = tobf(val + ep.gtab[row-col]);
        } else if constexpr (EPI==3) {
          size_t gr = (size_t)z*CHUNKC + row;
          ep.Cb[gr*EMBED + col] = tobf(val * frombf(ep.rb[gr*EMBED + col]));
        } else if constexpr (EPI==4) {
          float zz = val + ep.bias[col] + frombf(ep.hxb[(size_t)row*EMBED + col]);
          float hh = siluf_(zz);
          float res = ep.resid[(size_t)row*EMBED + col];
          ep.outp[(size_t)row*EMBED + col] = res + frombf(ep.ub[(size_t)row*EMBED + col])*(hh-res);
        } else if constexpr (EPI==6) {
          float zv = val + ep.bias[col];
          ep.f32o[(size_t)row*EMBED + col] = (zv > 15.f) ? zv : log1pf(__expf(zv));
        } else {  // EPI==7: v (cols<1024) + xdbl ride-along (cols 1024..1151)
          if (col < 1024) {
            ep.Cb[(size_t)row*ep.ldc + col] = tobf(siluf_(val + ep.bias[col]));
          } else {
            int jj = col - 1024;
            if (jj < XDBL_W) ep.f32o[(size_t)row*XDBL_W + jj] = val;
            if (jj < DTR)    ep.bf16o[(size_t)row*DTR + jj] = tobf(val);
          }
        }
      }
    }
  }
}

// ---------------------------------------------------------------- launch
extern "C" void kernel_launch(void* const* d_in, const int* in_sizes, int n_in,
                              void* d_out, int out_size, void* d_ws, size_t ws_size,
                              hipStream_t stream) {
  const float* x       = (const float*)d_in[0];
  const float* norm_w  = (const float*)d_in[1];
  const float* v_w     = (const float*)d_in[2];
  const float* v_b     = (const float*)d_in[3];
  const float* mx_w    = (const float*)d_in[4];
  const float* mx_b    = (const float*)d_in[5];
  const float* h_w     = (const float*)d_in[6];
  const float* h_b     = (const float*)d_in[7];
  const float* gamma   = (const float*)d_in[8];
  const float* beta    = (const float*)d_in[9];
  const float* alpha_rb= (const float*)d_in[10];
  const float* beta_rb = (const float*)d_in[11];
  const float* xproj_w = (const float*)d_in[12];
  const float* dt_w    = (const float*)d_in[13];
  const float* dt_b    = (const float*)d_in[14];
  const float* A_log   = (const float*)d_in[15];
  const float* D_p     = (const float*)d_in[16];
  float* out = (float*)d_out;

  float* ws = (float*)d_ws;
  size_t off = 0;
  auto alloc = [&](size_t n){ float* p = ws + off; off += n; return p; };
  const size_t BL2 = (size_t)BATCH*LSEQ; // 8192

  float* xn      = alloc(BL2*EMBED);        // f32; later aliased by Sb
  float* scratch = alloc((size_t)2*CHUNKC*CHUNKC*2); // dtb+seg*, then S(bf16)
  float* xdbl    = alloc(BL2*XDBL_W);
  float* gtab    = alloc(CHUNKC);
  auto balloc = [&](size_t nbf){ __hip_bfloat16* p = (__hip_bfloat16*)(ws + off); off += (nbf+1)/2; return p; };
  __hip_bfloat16* xnb   = balloc(BL2*EMBED);   // later reused as VT
  __hip_bfloat16* vbufb = balloc(BL2*EMBED);
  __hip_bfloat16* mxb   = balloc(BL2*EMBED);
  __hip_bfloat16* qb    = balloc(BL2*ZD);
  __hip_bfloat16* kb    = balloc(BL2*ZD);
  __hip_bfloat16* ugb   = balloc(BL2*EMBED);
  __hip_bfloat16* rbb   = balloc(BL2*EMBED);
  __hip_bfloat16* hxbb  = balloc(BL2*EMBED);
  __hip_bfloat16* hrb   = balloc(BL2*EMBED);
  __hip_bfloat16* xdblb = balloc(BL2*DTR);
  __hip_bfloat16* wcat  = balloc((size_t)1152*EMBED);  // [v_w(1024); xproj_w(96); pad(32)]
  __hip_bfloat16* mxwb  = balloc((size_t)3200*EMBED);
  __hip_bfloat16* hwb   = balloc((size_t)EMBED*EMBED);
  __hip_bfloat16* dtwb  = balloc((size_t)EMBED*DTR);

  float* dtb     = scratch;
  float* segP    = scratch + BL2*EMBED;
  float* segH    = segP + (size_t)NSEG*2048*NSTATE;
  float* segInit = segH + (size_t)NSEG*2048*NSTATE;
  __hip_bfloat16* S  = (__hip_bfloat16*)scratch;  // after scan (bf16 4*2048*2048)
  __hip_bfloat16* Sb = (__hip_bfloat16*)xn;       // after scan
  __hip_bfloat16* VT = xnb;                       // after v+xdbl GEMM

  // 0. unified prep: all weight converts + pad + gtab
  prep_k<<<5448, 256, 0, stream>>>(v_w, xproj_w, h_w, dt_w, mx_w,
                                   alpha_rb, beta_rb,
                                   wcat, hwb, dtwb, mxwb, gtab);

  // 1. rmsnorm
  rmsnorm_k<<<(int)BL2, 256, 0, stream>>>(x, norm_w, xn, xnb);

  MEp ep;

  // 2. v = silu(xn @ v_w^T + v_b) [cols<1024] + xdbl = xn @ xproj^T [cols 1024..1151]
  ep = {}; ep.bias = v_b; ep.Cb = vbufb; ep.ldc = EMBED;
  ep.f32o = xdbl; ep.bf16o = xdblb;
  mgemm_k<7,false,true><<<dim3(1152/MBM, BL2/MBM), 256, 0, stream>>>(
      xnb, EMBED, 0, wcat, EMBED, 0, EMBED, ep);

  // 3. dt = softplus(xdbl[:, :64] @ dt_w^T + dt_b)  (f32)
  ep = {}; ep.bias = dt_b; ep.f32o = dtb;
  mgemm_k<6,false,true><<<dim3(EMBED/MBM, BL2/MBM), 256, 0, stream>>>(
      xdblb, DTR, 0, dtwb, DTR, 0, DTR, ep);

  // 3b. transpose V per chunk (xnb dead now)
  transpose_k<<<dim3(EMBED/64, BL2/64), 256, 0, stream>>>(
      (const unsigned short*)vbufb, (unsigned short*)VT);

  // 4. segment-parallel scan -> mxb
  seg_scan_k<false><<<NSEG*8, 256, 0, stream>>>(xdbl, dtb, xn, A_log, D_p,
                                                nullptr, segP, segH, nullptr);
  seg_combine_k<<<128, 256, 0, stream>>>(segP, segH, segInit);
  seg_scan_k<true><<<NSEG*8, 256, 0, stream>>>(xdbl, dtb, xn, A_log, D_p,
                                               segInit, nullptr, nullptr, mxb);

  // 5. base = mx @ mx_w^T + mx_b, split epilogue
  ep = {}; ep.bias = mx_b; ep.gamma = gamma; ep.beta2 = beta;
  ep.ug = ugb; ep.qo = qb; ep.ko = kb; ep.ro = rbb; ep.hxo = hxbb;
  mgemm_k<1,false,true><<<dim3(3200/MBM, BL2/MBM), 256, 0, stream>>>(
      mxb, EMBED, 0, mxwb, EMBED, 0, EMBED, ep);

  // 6. QK^T + bias + mask -> bf16 S (upper-triangle tiles + stores skipped)
  ep = {}; ep.gtab = gtab; ep.Cb = S;
  mgemm_k<2,false,true><<<dim3(CHUNKC/MBM, CHUNKC/MBM, 4), 256, 0, stream>>>(
      qb, ZD, (long long)CHUNKC*ZD, kb, ZD, (long long)CHUNKC*ZD, ZD, ep);

  // 7. softmax (causal reads, writes clipped to PV-visible cols)
  softmax_k<<<4*CHUNKC, 256, 0, stream>>>(S, Sb);

  // 8. P@V, K clipped to diagonal, fused *r -> bf16
  ep = {}; ep.rb = rbb; ep.Cb = hrb;
  mgemm_k<3,true,true><<<dim3(EMBED/MBM, CHUNKC/MBM, 4), 256, 0, stream>>>(
      Sb, CHUNKC, (long long)CHUNKC*CHUNKC, VT, CHUNKC, (long long)EMBED*CHUNKC, CHUNKC, ep);

  // 9. final: h = silu(hx + (h*r) @ h_w^T + h_b); out = x + u*(h-x)
  ep = {}; ep.bias = h_b; ep.hxb = hxbb; ep.ub = ugb; ep.resid = x; ep.outp = out;
  mgemm_k<4,false,true><<<dim3(EMBED/MBM, BL2/MBM), 256, 0, stream>>>(
      hrb, EMBED, 0, hwb, EMBED, 0, EMBED, ep);
}

// Round 11
// 492.938 us; speedup vs baseline: 1.1150x; 1.0202x over previous
//
#include <hip/hip_runtime.h>
#include <hip/hip_bf16.h>
#include <math.h>

#define EMBED 1024
#define LSEQ 4096
#define BATCH 2
#define ZD 128
#define CHUNKC 2048
#define NSTATE 16
#define DTR 64
#define XDBL_W 96   // DT_RANK + 2*DSTATE
#define NSEG 64
#define TSEG 64     // LSEQ / NSEG

typedef __attribute__((ext_vector_type(8))) short bf16x8;
typedef __attribute__((ext_vector_type(4))) float f32x4;

__device__ __forceinline__ float sigmoidf_(float x){ return 1.f/(1.f+__expf(-x)); }
__device__ __forceinline__ float siluf_(float x){ return x/(1.f+__expf(-x)); }
__device__ __forceinline__ __hip_bfloat16 tobf(float x){ return __float2bfloat16(x); }
__device__ __forceinline__ float frombf(__hip_bfloat16 x){ return __bfloat162float(x); }

__device__ __forceinline__ void gload_lds16(const void* g, void* l) {
  __builtin_amdgcn_global_load_lds(
      (const __attribute__((address_space(1))) unsigned int*)g,
      (__attribute__((address_space(3))) unsigned int*)l, 16, 0, 0);
}

// ---------------------------------------------------------------- unified prep:
// block ranges: [0,1024) v_w->wcat ; [1024,1120) xproj->wcat+1M ; [1120,1152) zero-pad ;
// [1152,2176) h_w->hwb ; [2176,2240) dt_w->dtwb ; [2240,5440) mx_w->mxwb ; [5440,5448) gtab
__global__ __launch_bounds__(256) void prep_k(
    const float* __restrict__ v_w, const float* __restrict__ xproj_w,
    const float* __restrict__ h_w, const float* __restrict__ dt_w,
    const float* __restrict__ mx_w,
    const float* __restrict__ alpha, const float* __restrict__ beta,
    __hip_bfloat16* __restrict__ wcat, __hip_bfloat16* __restrict__ hwb,
    __hip_bfloat16* __restrict__ dtwb, __hip_bfloat16* __restrict__ mxwb,
    float* __restrict__ gtab)
{
  int b = blockIdx.x, tid = threadIdx.x;
  if (b < 5440) {
    const float* s; __hip_bfloat16* d; int idx;
    if (b < 1024)      { idx = (b*256+tid)*4;        s = v_w + idx;      d = wcat + idx; }
    else if (b < 1120) { idx = ((b-1024)*256+tid)*4; s = xproj_w + idx;  d = wcat + (1<<20) + idx; }
    else if (b < 1152) { idx = ((b-1120)*256+tid)*4; s = nullptr;        d = wcat + (1<<20) + 96*1024 + idx; }
    else if (b < 2176) { idx = ((b-1152)*256+tid)*4; s = h_w + idx;      d = hwb + idx; }
    else if (b < 2240) { idx = ((b-2176)*256+tid)*4; s = dt_w + idx;     d = dtwb + idx; }
    else               { idx = ((b-2240)*256+tid)*4; s = mx_w + idx;     d = mxwb + idx; }
    if (s) {
      float4 v = *(const float4*)s;
      d[0]=tobf(v.x); d[1]=tobf(v.y); d[2]=tobf(v.z); d[3]=tobf(v.w);
    } else {
      d[0]=tobf(0.f); d[1]=tobf(0.f); d[2]=tobf(0.f); d[3]=tobf(0.f);
    }
    return;
  }
  // gtab
  __shared__ float P[64], Q[64], F[64];
  if (tid < 64) {
    float a1=alpha[tid], a2=alpha[64+tid], b1=beta[tid], b2=beta[64+tid];
    P[tid]=a1*b1+a2*b2;
    Q[tid]=a2*b1-a1*b2;
    F[tid]=expf(-0.14391156831f*(float)tid); // ln(10000)/64
  }
  __syncthreads();
  int d = (b-5440)*256 + tid;
  if (d < CHUNKC) {
    float s=0.f;
    for (int j=0;j<64;++j){
      float th = (float)d * F[j];
      float sn, cs;
      sincosf(th, &sn, &cs);
      s += P[j]*cs - Q[j]*sn;
    }
    gtab[d]=s;
  }
}

// ---------------------------------------------------------------- rmsnorm (bf16 out only)
__global__ __launch_bounds__(256) void rmsnorm_k(const float* __restrict__ x,
                                                 const float* __restrict__ w,
                                                 __hip_bfloat16* __restrict__ xnb) {
  size_t row = blockIdx.x;
  const float* px = x + row*EMBED;
  int tid = threadIdx.x;
  float4 xv = *(const float4*)(px + tid*4);
  float ss = xv.x*xv.x + xv.y*xv.y + xv.z*xv.z + xv.w*xv.w;
  #pragma unroll
  for (int off=32; off; off>>=1) ss += __shfl_down(ss, off, 64);
  __shared__ float red[4];
  if ((tid&63)==0) red[tid>>6]=ss;
  __syncthreads();
  float tot = red[0]+red[1]+red[2]+red[3];
  float scale = rsqrtf(tot*(1.f/EMBED) + 1e-5f);
  float4 wv = *(const float4*)(w + tid*4);
  __hip_bfloat16* pb = xnb + row*EMBED + tid*4;
  pb[0]=tobf(xv.x*scale*wv.x); pb[1]=tobf(xv.y*scale*wv.y);
  pb[2]=tobf(xv.z*scale*wv.z); pb[3]=tobf(xv.w*scale*wv.w);
}

// ---------------------------------------------------------------- segment-parallel S6 scan
// inputs now bf16 (dt, u) + compact f32 B/C (xbc[row][32])
template<bool FINAL>
__global__ __launch_bounds__(256) void seg_scan_k(
    const float* __restrict__ xbc,
    const __hip_bfloat16* __restrict__ dtv,
    const __hip_bfloat16* __restrict__ xnu,
    const float* __restrict__ A_log,
    const float* __restrict__ D_p,
    const float* __restrict__ segInit,
    float* __restrict__ segP,
    float* __restrict__ segH,
    __hip_bfloat16* __restrict__ mx)
{
  int bx = blockIdx.x;
  int seg = bx >> 3;
  int grp = bx & 7;
  int b = grp >> 2;
  int d = (grp & 3)*256 + threadIdx.x;
  int ch = b*EMBED + d;
  int tid = threadIdx.x;
  int tbase = seg*TSEG;

  float A[NSTATE], h[NSTATE], P[NSTATE];
  #pragma unroll
  for (int n=0;n<NSTATE;++n){
    A[n] = -__expf(A_log[(size_t)d*NSTATE+n]);
    P[n] = 1.f;
  }
  if (FINAL) {
    const float* si = segInit + ((size_t)seg*2048 + ch)*NSTATE;
    #pragma unroll
    for (int n=0;n<NSTATE;++n) h[n] = si[n];
  } else {
    #pragma unroll
    for (int n=0;n<NSTATE;++n) h[n] = 0.f;
  }
  float Dp = FINAL ? D_p[d] : 0.f;

  __shared__ float BCb[8][32];
  const float* xd = xbc + ((size_t)b*LSEQ + tbase)*32;
  const __hip_bfloat16* pdt = dtv + ((size_t)b*LSEQ + tbase)*EMBED + d;
  const __hip_bfloat16* pu  = xnu + ((size_t)b*LSEQ + tbase)*EMBED + d;
  __hip_bfloat16* pmx = mx + ((size_t)b*LSEQ + tbase)*EMBED + d;

  for (int t0=0; t0<TSEG; t0+=8) {
    __syncthreads();
    { int tt = tid>>5, jj = tid&31;
      BCb[tt][jj] = xd[(size_t)(t0+tt)*32 + jj]; }
    __syncthreads();
    #pragma unroll
    for (int tt=0; tt<8; ++tt) {
      int t = t0 + tt;
      float dtt = frombf(pdt[(size_t)t*EMBED]);
      float ut  = frombf(pu[(size_t)t*EMBED]);
      float du = dtt*ut;
      float y = 0.f;
      #pragma unroll
      for (int n=0;n<NSTATE;++n){
        float dA = __expf(dtt*A[n]);
        h[n] = dA*h[n] + du*BCb[tt][n];
        if (!FINAL) P[n] *= dA;
        if (FINAL)  y += h[n]*BCb[tt][16+n];
      }
      if (FINAL) pmx[(size_t)t*EMBED] = tobf(siluf_(y + ut*Dp));
    }
  }
  if (!FINAL) {
    float* pp = segP + ((size_t)seg*2048 + ch)*NSTATE;
    float* ph = segH + ((size_t)seg*2048 + ch)*NSTATE;
    #pragma unroll
    for (int n=0;n<NSTATE;n+=4){
      *(float4*)(pp+n) = make_float4(P[n],P[n+1],P[n+2],P[n+3]);
      *(float4*)(ph+n) = make_float4(h[n],h[n+1],h[n+2],h[n+3]);
    }
  }
}

__global__ __launch_bounds__(256) void seg_combine_k(const float* __restrict__ segP,
                                                     const float* __restrict__ segH,
                                                     float* __restrict__ segInit) {
  int idx = blockIdx.x*256 + threadIdx.x;
  float H = 0.f;
  for (int s=0; s<NSEG; ++s) {
    size_t o = (size_t)s*32768 + idx;
    float Pv = segP[o], hl = segH[o];
    segInit[o] = H;
    H = Pv*H + hl;
  }
}

// ---------------------------------------------------------------- row softmax (bf16 in, bf16 out)
// causal-aware reads; writes clipped to kcl = 128*ceil((r+1)/128)
__global__ __launch_bounds__(256) void softmax_k(const __hip_bfloat16* __restrict__ S,
                                                 __hip_bfloat16* __restrict__ Sb) {
  size_t row = blockIdx.x;
  const __hip_bfloat16* p = S + row*CHUNKC;
  __hip_bfloat16* po = Sb + row*CHUNKC;
  int tid = threadIdx.x;
  int r = (int)(row & (CHUNKC-1));
  int nb = (r >> 8) + 1;
  int kcl = ((r >> 7) + 1) << 7;
  float v[8];
  float m = -1e30f;
  #pragma unroll
  for (int i=0;i<8;++i){
    if (i < nb) {
      float t = frombf(p[tid + i*256]);
      v[i] = (i*256 + tid <= r) ? t : -1e30f;
    } else v[i] = -1e30f;
    m = fmaxf(m, v[i]);
  }
  #pragma unroll
  for (int off=32; off; off>>=1) m = fmaxf(m, __shfl_down(m, off, 64));
  __shared__ float red[4];
  if ((tid&63)==0) red[tid>>6]=m;
  __syncthreads();
  m = fmaxf(fmaxf(red[0],red[1]),fmaxf(red[2],red[3]));
  float s=0.f;
  #pragma unroll
  for (int i=0;i<8;++i){ v[i]=__expf(v[i]-m); s+=v[i]; }
  #pragma unroll
  for (int off=32; off; off>>=1) s += __shfl_down(s, off, 64);
  __syncthreads();
  if ((tid&63)==0) red[tid>>6]=s;
  __syncthreads();
  s = red[0]+red[1]+red[2]+red[3];
  float inv = 1.f/s;
  #pragma unroll
  for (int i=0;i<8;++i){
    int c = tid + i*256;
    if (c < kcl) po[c] = tobf(v[i]*inv);
  }
}

// ---------------------------------------------------------------- bf16 transpose V -> VT[c][n][k]
__global__ __launch_bounds__(256) void transpose_k(const unsigned short* __restrict__ vb,
                                                   unsigned short* __restrict__ VT) {
  __shared__ unsigned short t[64][68];
  int tid = threadIdx.x;
  int tr = tid>>4;
  int tc = (tid&15)*4;
  int c0 = blockIdx.x*64, r0 = blockIdx.y*64;
  #pragma unroll
  for (int it=0; it<4; ++it) {
    int r = it*16 + tr;
    ushort4 v = *(const ushort4*)(vb + (size_t)(r0+r)*EMBED + c0 + tc);
    t[r][tc+0]=v.x; t[r][tc+1]=v.y; t[r][tc+2]=v.z; t[r][tc+3]=v.w;
  }
  __syncthreads();
  int ch = r0 >> 11;
  int kb = r0 & 2047;
  #pragma unroll
  for (int it=0; it<4; ++it) {
    int nl = it*16 + tr;
    ushort4 o;
    o.x = t[tc+0][nl]; o.y = t[tc+1][nl]; o.z = t[tc+2][nl]; o.w = t[tc+3][nl];
    *(ushort4*)(VT + ((size_t)ch*EMBED + c0 + nl)*CHUNKC + kb + tc) = o;
  }
}

// ---------------------------------------------------------------- bf16 MFMA GEMM
// 128x128 tile, BK=64, double-buffered LDS, XOR-swizzled staging/reads,
// counted-vmcnt pipeline, bijective XCD swizzle.
// EPI: 1 base-split; 2 QK bias+mask->bf16 lower-tri; 3 PV*r->bf16 (TRIK);
//      4 final gate->f32; 6 dt softplus->bf16; 7 v+xdbl merged (compact B/C)
struct MEp {
  const float* bias; const float* gtab; const float* gamma; const float* beta2;
  __hip_bfloat16* ug; __hip_bfloat16* qo; __hip_bfloat16* ko; __hip_bfloat16* ro; __hip_bfloat16* hxo;
  const __hip_bfloat16* rb; const __hip_bfloat16* hxb; const __hip_bfloat16* ub;
  const float* resid; float* outp;
  __hip_bfloat16* Cb; int ldc;
  float* f32o; __hip_bfloat16* bf16o;
};

__device__ __forceinline__ void xcd_swz(int& bx, int& by) {
  const int gx = gridDim.x;
  const int nwg = gx*gridDim.y;
  const int lin = by*gx + bx;
  const int qq = nwg >> 3, rr = nwg & 7;
  const int xcd = lin & 7, pos = lin >> 3;
  const int base = (xcd < rr) ? xcd*(qq+1) : rr*(qq+1) + (xcd-rr)*qq;
  const int lg = base + pos;
  bx = lg % gx; by = lg / gx;
}

#define MBM 128
#define MBK 64

template<int EPI, bool TRIK, bool SWZ>
__global__ __launch_bounds__(256, 3) void mgemm_k(
    const __hip_bfloat16* __restrict__ A, int lda, long long sAz,
    const __hip_bfloat16* __restrict__ B, int ldb, long long sBz,
    int K, MEp ep)
{
  __shared__ __attribute__((aligned(16))) short As[2][MBM*MBK];
  __shared__ __attribute__((aligned(16))) short Bs[2][MBM*MBK];
  const int tid = threadIdx.x;
  const int wv = tid>>6, lane = tid&63;
  const int z = blockIdx.z;
  A += (size_t)z * sAz;
  B += (size_t)z * sBz;
  int bx = blockIdx.x, by = blockIdx.y;
  if constexpr (SWZ) xcd_swz(bx, by);
  const int m0 = by*MBM, n0 = bx*MBM;
  if constexpr (EPI==2) { if (n0 > m0 + (MBM-1)) return; }
  const int r8 = lane>>3, g8 = lane&7;
  const int csrc = g8 ^ r8;
  const int wr = wv>>1, wc = wv&1;
  const int fr = lane&15, qv = lane>>4;
  const int x7 = fr & 7;

  int Ktot = K;
  if constexpr (TRIK) { int km = m0 + MBM; Ktot = km < K ? km : K; }
  const int nt = Ktot / MBK;

  f32x4 acc[4][4] = {};

  const __hip_bfloat16* Ag = A + (size_t)(m0 + wv*32 + r8)*lda + csrc*8;
  const __hip_bfloat16* Bg = B + (size_t)(n0 + wv*32 + r8)*ldb + csrc*8;

  auto stage = [&](int buf, int t){
    const int k0 = t*MBK;
    short* Al = &As[buf][wv*32*MBK];
    short* Bl = &Bs[buf][wv*32*MBK];
    #pragma unroll
    for (int j=0;j<4;++j)
      gload_lds16(Ag + (size_t)(j*8)*lda + k0, Al + j*8*MBK);
    #pragma unroll
    for (int j=0;j<4;++j)
      gload_lds16(Bg + (size_t)(j*8)*ldb + k0, Bl + j*8*MBK);
  };

  // prologue: fill both buffers, wait only buf0 (counted)
  stage(0, 0);
  if (nt > 1) {
    stage(1, 1);
    asm volatile("s_waitcnt vmcnt(8)" ::: "memory");
  } else {
    asm volatile("s_waitcnt vmcnt(0)" ::: "memory");
  }
  __builtin_amdgcn_sched_barrier(0);
  __builtin_amdgcn_s_barrier();

  for (int t=0; t<nt; ++t) {
    const int cur = t & 1;
    const short* Ab = &As[cur][0];
    const short* Bb = &Bs[cur][0];
    #pragma unroll
    for (int kk=0; kk<2; ++kk) {
      const int pos8 = ((kk*4 + qv) ^ x7) * 8;
      bf16x8 af[4], bfr[4];
      #pragma unroll
      for (int mi=0;mi<4;++mi)
        af[mi] = *(const bf16x8*)&Ab[(wr*64 + mi*16 + fr)*MBK + pos8];
      #pragma unroll
      for (int ni=0;ni<4;++ni)
        bfr[ni] = *(const bf16x8*)&Bb[(wc*64 + ni*16 + fr)*MBK + pos8];
      #pragma unroll
      for (int mi=0;mi<4;++mi)
        #pragma unroll
        for (int ni=0;ni<4;++ni)
          acc[mi][ni] = __builtin_amdgcn_mfma_f32_16x16x32_bf16(af[mi], bfr[ni], acc[mi][ni], 0,0,0);
    }
    if (t+1 >= nt) break;
    __builtin_amdgcn_sched_barrier(0);
    __builtin_amdgcn_s_barrier();            // all waves done reading buf[cur]
    if (t+2 < nt) {
      stage(cur, t+2);
      asm volatile("s_waitcnt vmcnt(8)" ::: "memory");   // t+1's loads done; t+2's in flight
    } else {
      asm volatile("s_waitcnt vmcnt(0)" ::: "memory");
    }
    __builtin_amdgcn_sched_barrier(0);
    __builtin_amdgcn_s_barrier();            // buf[cur^1] ready on all waves
  }

  const int vr = (lane>>4)*4;
  #pragma unroll
  for (int mi=0;mi<4;++mi) {
    #pragma unroll
    for (int v=0; v<4; ++v) {
      const int row = m0 + wr*64 + mi*16 + vr + v;
      #pragma unroll
      for (int ni=0;ni<4;++ni) {
        const int col = n0 + wc*64 + ni*16 + fr;
        float val = acc[mi][ni][v];
        if constexpr (EPI==1) {
          val += ep.bias[col];
          if (col < 1024) {
            ep.ug[(size_t)row*EMBED + col] = tobf(sigmoidf_(val));
          } else if (col < 1152) {
            int jj = col - 1024;
            float zz = siluf_(val);
            ep.qo[(size_t)row*ZD + jj] = tobf((zz*ep.gamma[jj] + ep.beta2[jj]) * 0.08838834764831845f);
            ep.ko[(size_t)row*ZD + jj] = tobf(zz*ep.gamma[128+jj] + ep.beta2[128+jj]);
          } else if (col < 2176) {
            ep.ro[(size_t)row*EMBED + (col-1152)] = tobf(siluf_(val));
          } else {
            ep.hxo[(size_t)row*EMBED + (col-2176)] = tobf(val);
          }
        } else if constexpr (EPI==2) {
          __hip_bfloat16* Sp = ep.Cb + (size_t)z*CHUNKC*CHUNKC;
          if (col <= row) Sp[(size_t)row*CHUNKC + col] = tobf(val + ep.gtab[row-col]);
        } else if constexpr (EPI==3) {
          size_t gr = (size_t)z*CHUNKC + row;
          ep.Cb[gr*EMBED + col] = tobf(val * frombf(ep.rb[gr*EMBED + col]));
        } else if constexpr (EPI==4) {
          float zz = val + ep.bias[col] + frombf(ep.hxb[(size_t)row*EMBED + col]);
          float hh = siluf_(zz);
          float res = ep.resid[(size_t)row*EMBED + col];
          ep.outp[(size_t)row*EMBED + col] = res + frombf(ep.ub[(size_t)row*EMBED + col])*(hh-res);
        } else if constexpr (EPI==6) {
          float zv = val + ep.bias[col];
          ep.bf16o[(size_t)row*EMBED + col] = tobf((zv > 15.f) ? zv : log1pf(__expf(zv)));
        } else {  // EPI==7: v (cols<1024) + xdbl ride-along: dt-input bf16 (64) + compact B/C f32 (32)
          if (col < 1024) {
            ep.Cb[(size_t)row*ep.ldc + col] = tobf(siluf_(val + ep.bias[col]));
          } else {
            int jj = col - 1024;
            if (jj < DTR)          ep.bf16o[(size_t)row*DTR + jj] = tobf(val);
            else if (jj < XDBL_W)  ep.f32o[(size_t)row*32 + (jj - DTR)] = val;
          }
        }
      }
    }
  }
}

// ---------------------------------------------------------------- launch
extern "C" void kernel_launch(void* const* d_in, const int* in_sizes, int n_in,
                              void* d_out, int out_size, void* d_ws, size_t ws_size,
                              hipStream_t stream) {
  const float* x       = (const float*)d_in[0];
  const float* norm_w  = (const float*)d_in[1];
  const float* v_w     = (const float*)d_in[2];
  const float* v_b     = (const float*)d_in[3];
  const float* mx_w    = (const float*)d_in[4];
  const float* mx_b    = (const float*)d_in[5];
  const float* h_w     = (const float*)d_in[6];
  const float* h_b     = (const float*)d_in[7];
  const float* gamma   = (const float*)d_in[8];
  const float* beta    = (const float*)d_in[9];
  const float* alpha_rb= (const float*)d_in[10];
  const float* beta_rb = (const float*)d_in[11];
  const float* xproj_w = (const float*)d_in[12];
  const float* dt_w    = (const float*)d_in[13];
  const float* dt_b    = (const float*)d_in[14];
  const float* A_log   = (const float*)d_in[15];
  const float* D_p     = (const float*)d_in[16];
  float* out = (float*)d_out;

  float* ws = (float*)d_ws;
  size_t off = 0;
  auto alloc = [&](size_t n){ float* p = ws + off; off += n; return p; };
  const size_t BL2 = (size_t)BATCH*LSEQ; // 8192

  float* sbzone  = alloc(BL2*EMBED);        // Sb (bf16 4*2048*2048) lives here
  float* scratch = alloc((size_t)2*CHUNKC*CHUNKC*2); // dtbb+seg*, then S(bf16)
  float* xbc     = alloc(BL2*32);           // compact B/C f32 [row][32]
  float* gtab    = alloc(CHUNKC);
  auto balloc = [&](size_t nbf){ __hip_bfloat16* p = (__hip_bfloat16*)(ws + off); off += (nbf+1)/2; return p; };
  __hip_bfloat16* xnb   = balloc(BL2*EMBED);   // later reused as VT (after scan)
  __hip_bfloat16* vbufb = balloc(BL2*EMBED);
  __hip_bfloat16* mxb   = balloc(BL2*EMBED);
  __hip_bfloat16* qb    = balloc(BL2*ZD);
  __hip_bfloat16* kb    = balloc(BL2*ZD);
  __hip_bfloat16* ugb   = balloc(BL2*EMBED);
  __hip_bfloat16* rbb   = balloc(BL2*EMBED);
  __hip_bfloat16* hxbb  = balloc(BL2*EMBED);
  __hip_bfloat16* hrb   = balloc(BL2*EMBED);
  __hip_bfloat16* xdblb = balloc(BL2*DTR);
  __hip_bfloat16* wcat  = balloc((size_t)1152*EMBED);  // [v_w(1024); xproj_w(96); pad(32)]
  __hip_bfloat16* mxwb  = balloc((size_t)3200*EMBED);
  __hip_bfloat16* hwb   = balloc((size_t)EMBED*EMBED);
  __hip_bfloat16* dtwb  = balloc((size_t)EMBED*DTR);

  __hip_bfloat16* dtbb = (__hip_bfloat16*)scratch;     // bf16 [BL2][EMBED]
  float* segP    = scratch + BL2*EMBED;                // offsets unchanged (room freed by bf16 dt)
  float* segH    = segP + (size_t)NSEG*2048*NSTATE;
  float* segInit = segH + (size_t)NSEG*2048*NSTATE;
  __hip_bfloat16* S  = (__hip_bfloat16*)scratch;  // after scan (bf16 4*2048*2048)
  __hip_bfloat16* Sb = (__hip_bfloat16*)sbzone;   // after scan
  __hip_bfloat16* VT = xnb;                       // after scan pass 3

  // 0. unified prep: all weight converts + pad + gtab
  prep_k<<<5448, 256, 0, stream>>>(v_w, xproj_w, h_w, dt_w, mx_w,
                                   alpha_rb, beta_rb,
                                   wcat, hwb, dtwb, mxwb, gtab);

  // 1. rmsnorm (bf16 only)
  rmsnorm_k<<<(int)BL2, 256, 0, stream>>>(x, norm_w, xnb);

  MEp ep;

  // 2. v = silu(xn @ v_w^T + v_b) [cols<1024] + dt-input bf16 + compact B/C [cols 1024..1119]
  ep = {}; ep.bias = v_b; ep.Cb = vbufb; ep.ldc = EMBED;
  ep.f32o = xbc; ep.bf16o = xdblb;
  mgemm_k<7,false,true><<<dim3(1152/MBM, BL2/MBM), 256, 0, stream>>>(
      xnb, EMBED, 0, wcat, EMBED, 0, EMBED, ep);

  // 3. dt = softplus(xdbl[:, :64] @ dt_w^T + dt_b)  (bf16 out)
  ep = {}; ep.bias = dt_b; ep.bf16o = dtbb;
  mgemm_k<6,false,true><<<dim3(EMBED/MBM, BL2/MBM), 256, 0, stream>>>(
      xdblb, DTR, 0, dtwb, DTR, 0, DTR, ep);

  // 4. segment-parallel scan -> mxb (reads bf16 dt/u + compact f32 B/C)
  seg_scan_k<false><<<NSEG*8, 256, 0, stream>>>(xbc, dtbb, xnb, A_log, D_p,
                                                nullptr, segP, segH, nullptr);
  seg_combine_k<<<128, 256, 0, stream>>>(segP, segH, segInit);
  seg_scan_k<true><<<NSEG*8, 256, 0, stream>>>(xbc, dtbb, xnb, A_log, D_p,
                                               segInit, nullptr, nullptr, mxb);

  // 4b. transpose V per chunk (xnb dead now -> VT)
  transpose_k<<<dim3(EMBED/64, BL2/64), 256, 0, stream>>>(
      (const unsigned short*)vbufb, (unsigned short*)VT);

  // 5. base = mx @ mx_w^T + mx_b, split epilogue
  ep = {}; ep.bias = mx_b; ep.gamma = gamma; ep.beta2 = beta;
  ep.ug = ugb; ep.qo = qb; ep.ko = kb; ep.ro = rbb; ep.hxo = hxbb;
  mgemm_k<1,false,true><<<dim3(3200/MBM, BL2/MBM), 256, 0, stream>>>(
      mxb, EMBED, 0, mxwb, EMBED, 0, EMBED, ep);

  // 6. QK^T + bias + mask -> bf16 S (upper-triangle tiles + stores skipped)
  ep = {}; ep.gtab = gtab; ep.Cb = S;
  mgemm_k<2,false,true><<<dim3(CHUNKC/MBM, CHUNKC/MBM, 4), 256, 0, stream>>>(
      qb, ZD, (long long)CHUNKC*ZD, kb, ZD, (long long)CHUNKC*ZD, ZD, ep);

  // 7. softmax (causal reads, writes clipped to PV-visible cols)
  softmax_k<<<4*CHUNKC, 256, 0, stream>>>(S, Sb);

  // 8. P@V, K clipped to diagonal, fused *r -> bf16
  ep = {}; ep.rb = rbb; ep.Cb = hrb;
  mgemm_k<3,true,true><<<dim3(EMBED/MBM, CHUNKC/MBM, 4), 256, 0, stream>>>(
      Sb, CHUNKC, (long long)CHUNKC*CHUNKC, VT, CHUNKC, (long long)EMBED*CHUNKC, CHUNKC, ep);

  // 9. final: h = silu(hx + (h*r) @ h_w^T + h_b); out = x + u*(h-x)
  ep = {}; ep.bias = h_b; ep.hxb = hxbb; ep.ub = ugb; ep.resid = x; ep.outp = out;
  mgemm_k<4,false,true><<<dim3(EMBED/MBM, BL2/MBM), 256, 0, stream>>>(
      hrb, EMBED, 0, hwb, EMBED, 0, EMBED, ep);
}

// Round 12
// 414.399 us; speedup vs baseline: 1.3263x; 1.1895x over previous
//
#include <hip/hip_runtime.h>
#include <hip/hip_bf16.h>
#include <math.h>

#define EMBED 1024
#define LSEQ 4096
#define BATCH 2
#define ZD 128
#define CHUNKC 2048
#define NSTATE 16
#define DTR 64
#define XDBL_W 96   // DT_RANK + 2*DSTATE
#define NSEG 64
#define TSEG 64     // LSEQ / NSEG

typedef __attribute__((ext_vector_type(8))) short bf16x8;
typedef __attribute__((ext_vector_type(4))) float f32x4;

__device__ __forceinline__ float sigmoidf_(float x){ return 1.f/(1.f+__expf(-x)); }
__device__ __forceinline__ float siluf_(float x){ return x/(1.f+__expf(-x)); }
__device__ __forceinline__ __hip_bfloat16 tobf(float x){ return __float2bfloat16(x); }
__device__ __forceinline__ float frombf(__hip_bfloat16 x){ return __bfloat162float(x); }

__device__ __forceinline__ void gload_lds16(const void* g, void* l) {
  __builtin_amdgcn_global_load_lds(
      (const __attribute__((address_space(1))) unsigned int*)g,
      (__attribute__((address_space(3))) unsigned int*)l, 16, 0, 0);
}

// ---------------------------------------------------------------- unified prep:
// block ranges: [0,1024) v_w->wcat ; [1024,1120) xproj->wcat+1M ; [1120,1152) zero-pad ;
// [1152,2176) h_w->hwb ; [2176,2240) dt_w->dtwb ; [2240,5440) mx_w->mxwb ; [5440,5448) gtab
__global__ __launch_bounds__(256) void prep_k(
    const float* __restrict__ v_w, const float* __restrict__ xproj_w,
    const float* __restrict__ h_w, const float* __restrict__ dt_w,
    const float* __restrict__ mx_w,
    const float* __restrict__ alpha, const float* __restrict__ beta,
    __hip_bfloat16* __restrict__ wcat, __hip_bfloat16* __restrict__ hwb,
    __hip_bfloat16* __restrict__ dtwb, __hip_bfloat16* __restrict__ mxwb,
    float* __restrict__ gtab)
{
  int b = blockIdx.x, tid = threadIdx.x;
  if (b < 5440) {
    const float* s; __hip_bfloat16* d; int idx;
    if (b < 1024)      { idx = (b*256+tid)*4;        s = v_w + idx;      d = wcat + idx; }
    else if (b < 1120) { idx = ((b-1024)*256+tid)*4; s = xproj_w + idx;  d = wcat + (1<<20) + idx; }
    else if (b < 1152) { idx = ((b-1120)*256+tid)*4; s = nullptr;        d = wcat + (1<<20) + 96*1024 + idx; }
    else if (b < 2176) { idx = ((b-1152)*256+tid)*4; s = h_w + idx;      d = hwb + idx; }
    else if (b < 2240) { idx = ((b-2176)*256+tid)*4; s = dt_w + idx;     d = dtwb + idx; }
    else               { idx = ((b-2240)*256+tid)*4; s = mx_w + idx;     d = mxwb + idx; }
    if (s) {
      float4 v = *(const float4*)s;
      d[0]=tobf(v.x); d[1]=tobf(v.y); d[2]=tobf(v.z); d[3]=tobf(v.w);
    } else {
      d[0]=tobf(0.f); d[1]=tobf(0.f); d[2]=tobf(0.f); d[3]=tobf(0.f);
    }
    return;
  }
  // gtab
  __shared__ float P[64], Q[64], F[64];
  if (tid < 64) {
    float a1=alpha[tid], a2=alpha[64+tid], b1=beta[tid], b2=beta[64+tid];
    P[tid]=a1*b1+a2*b2;
    Q[tid]=a2*b1-a1*b2;
    F[tid]=expf(-0.14391156831f*(float)tid); // ln(10000)/64
  }
  __syncthreads();
  int d = (b-5440)*256 + tid;
  if (d < CHUNKC) {
    float s=0.f;
    for (int j=0;j<64;++j){
      float th = (float)d * F[j];
      float sn, cs;
      sincosf(th, &sn, &cs);
      s += P[j]*cs - Q[j]*sn;
    }
    gtab[d]=s;
  }
}

// ---------------------------------------------------------------- rmsnorm (bf16 out only)
__global__ __launch_bounds__(256) void rmsnorm_k(const float* __restrict__ x,
                                                 const float* __restrict__ w,
                                                 __hip_bfloat16* __restrict__ xnb) {
  size_t row = blockIdx.x;
  const float* px = x + row*EMBED;
  int tid = threadIdx.x;
  float4 xv = *(const float4*)(px + tid*4);
  float ss = xv.x*xv.x + xv.y*xv.y + xv.z*xv.z + xv.w*xv.w;
  #pragma unroll
  for (int off=32; off; off>>=1) ss += __shfl_down(ss, off, 64);
  __shared__ float red[4];
  if ((tid&63)==0) red[tid>>6]=ss;
  __syncthreads();
  float tot = red[0]+red[1]+red[2]+red[3];
  float scale = rsqrtf(tot*(1.f/EMBED) + 1e-5f);
  float4 wv = *(const float4*)(w + tid*4);
  __hip_bfloat16* pb = xnb + row*EMBED + tid*4;
  pb[0]=tobf(xv.x*scale*wv.x); pb[1]=tobf(xv.y*scale*wv.y);
  pb[2]=tobf(xv.z*scale*wv.z); pb[3]=tobf(xv.w*scale*wv.w);
}

// ---------------------------------------------------------------- segment-parallel S6 scan
// inputs bf16 (dt, u) + compact f32 B/C (xbc[row][32])
template<bool FINAL>
__global__ __launch_bounds__(256) void seg_scan_k(
    const float* __restrict__ xbc,
    const __hip_bfloat16* __restrict__ dtv,
    const __hip_bfloat16* __restrict__ xnu,
    const float* __restrict__ A_log,
    const float* __restrict__ D_p,
    const float* __restrict__ segInit,
    float* __restrict__ segP,
    float* __restrict__ segH,
    __hip_bfloat16* __restrict__ mx)
{
  int bx = blockIdx.x;
  int seg = bx >> 3;
  int grp = bx & 7;
  int b = grp >> 2;
  int d = (grp & 3)*256 + threadIdx.x;
  int ch = b*EMBED + d;
  int tid = threadIdx.x;
  int tbase = seg*TSEG;

  float A[NSTATE], h[NSTATE], P[NSTATE];
  #pragma unroll
  for (int n=0;n<NSTATE;++n){
    A[n] = -__expf(A_log[(size_t)d*NSTATE+n]);
    P[n] = 1.f;
  }
  if (FINAL) {
    const float* si = segInit + ((size_t)seg*2048 + ch)*NSTATE;
    #pragma unroll
    for (int n=0;n<NSTATE;++n) h[n] = si[n];
  } else {
    #pragma unroll
    for (int n=0;n<NSTATE;++n) h[n] = 0.f;
  }
  float Dp = FINAL ? D_p[d] : 0.f;

  __shared__ float BCb[8][32];
  const float* xd = xbc + ((size_t)b*LSEQ + tbase)*32;
  const __hip_bfloat16* pdt = dtv + ((size_t)b*LSEQ + tbase)*EMBED + d;
  const __hip_bfloat16* pu  = xnu + ((size_t)b*LSEQ + tbase)*EMBED + d;
  __hip_bfloat16* pmx = mx + ((size_t)b*LSEQ + tbase)*EMBED + d;

  for (int t0=0; t0<TSEG; t0+=8) {
    __syncthreads();
    { int tt = tid>>5, jj = tid&31;
      BCb[tt][jj] = xd[(size_t)(t0+tt)*32 + jj]; }
    __syncthreads();
    #pragma unroll
    for (int tt=0; tt<8; ++tt) {
      int t = t0 + tt;
      float dtt = frombf(pdt[(size_t)t*EMBED]);
      float ut  = frombf(pu[(size_t)t*EMBED]);
      float du = dtt*ut;
      float y = 0.f;
      #pragma unroll
      for (int n=0;n<NSTATE;++n){
        float dA = __expf(dtt*A[n]);
        h[n] = dA*h[n] + du*BCb[tt][n];
        if (!FINAL) P[n] *= dA;
        if (FINAL)  y += h[n]*BCb[tt][16+n];
      }
      if (FINAL) pmx[(size_t)t*EMBED] = tobf(siluf_(y + ut*Dp));
    }
  }
  if (!FINAL) {
    float* pp = segP + ((size_t)seg*2048 + ch)*NSTATE;
    float* ph = segH + ((size_t)seg*2048 + ch)*NSTATE;
    #pragma unroll
    for (int n=0;n<NSTATE;n+=4){
      *(float4*)(pp+n) = make_float4(P[n],P[n+1],P[n+2],P[n+3]);
      *(float4*)(ph+n) = make_float4(h[n],h[n+1],h[n+2],h[n+3]);
    }
  }
}

__global__ __launch_bounds__(256) void seg_combine_k(const float* __restrict__ segP,
                                                     const float* __restrict__ segH,
                                                     float* __restrict__ segInit) {
  int idx = blockIdx.x*256 + threadIdx.x;
  float H = 0.f;
  for (int s=0; s<NSEG; ++s) {
    size_t o = (size_t)s*32768 + idx;
    float Pv = segP[o], hl = segH[o];
    segInit[o] = H;
    H = Pv*H + hl;
  }
}

// ---------------------------------------------------------------- row softmax (bf16 in, bf16 out)
// causal-aware reads; writes clipped to kcl = 128*ceil((r+1)/128)
__global__ __launch_bounds__(256) void softmax_k(const __hip_bfloat16* __restrict__ S,
                                                 __hip_bfloat16* __restrict__ Sb) {
  size_t row = blockIdx.x;
  const __hip_bfloat16* p = S + row*CHUNKC;
  __hip_bfloat16* po = Sb + row*CHUNKC;
  int tid = threadIdx.x;
  int r = (int)(row & (CHUNKC-1));
  int nb = (r >> 8) + 1;
  int kcl = ((r >> 7) + 1) << 7;
  float v[8];
  float m = -1e30f;
  #pragma unroll
  for (int i=0;i<8;++i){
    if (i < nb) {
      float t = frombf(p[tid + i*256]);
      v[i] = (i*256 + tid <= r) ? t : -1e30f;
    } else v[i] = -1e30f;
    m = fmaxf(m, v[i]);
  }
  #pragma unroll
  for (int off=32; off; off>>=1) m = fmaxf(m, __shfl_down(m, off, 64));
  __shared__ float red[4];
  if ((tid&63)==0) red[tid>>6]=m;
  __syncthreads();
  m = fmaxf(fmaxf(red[0],red[1]),fmaxf(red[2],red[3]));
  float s=0.f;
  #pragma unroll
  for (int i=0;i<8;++i){ v[i]=__expf(v[i]-m); s+=v[i]; }
  #pragma unroll
  for (int off=32; off; off>>=1) s += __shfl_down(s, off, 64);
  __syncthreads();
  if ((tid&63)==0) red[tid>>6]=s;
  __syncthreads();
  s = red[0]+red[1]+red[2]+red[3];
  float inv = 1.f/s;
  #pragma unroll
  for (int i=0;i<8;++i){
    int c = tid + i*256;
    if (c < kcl) po[c] = tobf(v[i]*inv);
  }
}

// ---------------------------------------------------------------- bf16 transpose V -> VT[c][n][k]
__global__ __launch_bounds__(256) void transpose_k(const unsigned short* __restrict__ vb,
                                                   unsigned short* __restrict__ VT) {
  __shared__ unsigned short t[64][68];
  int tid = threadIdx.x;
  int tr = tid>>4;
  int tc = (tid&15)*4;
  int c0 = blockIdx.x*64, r0 = blockIdx.y*64;
  #pragma unroll
  for (int it=0; it<4; ++it) {
    int r = it*16 + tr;
    ushort4 v = *(const ushort4*)(vb + (size_t)(r0+r)*EMBED + c0 + tc);
    t[r][tc+0]=v.x; t[r][tc+1]=v.y; t[r][tc+2]=v.z; t[r][tc+3]=v.w;
  }
  __syncthreads();
  int ch = r0 >> 11;
  int kb = r0 & 2047;
  #pragma unroll
  for (int it=0; it<4; ++it) {
    int nl = it*16 + tr;
    ushort4 o;
    o.x = t[tc+0][nl]; o.y = t[tc+1][nl]; o.z = t[tc+2][nl]; o.w = t[tc+3][nl];
    *(ushort4*)(VT + ((size_t)ch*EMBED + c0 + nl)*CHUNKC + kb + tc) = o;
  }
}

// ---------------------------------------------------------------- bf16 MFMA GEMM
// 128x128 tile, BK=64, SINGLE-buffered LDS (32 KB -> 4-5 resident blocks/CU;
// m97 mechanism: inter-block overlap hides the stage drain), XOR-swizzled
// staging/reads (0 conflicts), bijective XCD swizzle, launch_bounds(256,4).
// EPI: 1 base-split; 2 QK bias+mask->bf16 lower-tri; 3 PV*r->bf16 (TRIK);
//      4 final gate->f32; 6 dt softplus->bf16; 7 v+xdbl merged (compact B/C)
struct MEp {
  const float* bias; const float* gtab; const float* gamma; const float* beta2;
  __hip_bfloat16* ug; __hip_bfloat16* qo; __hip_bfloat16* ko; __hip_bfloat16* ro; __hip_bfloat16* hxo;
  const __hip_bfloat16* rb; const __hip_bfloat16* hxb; const __hip_bfloat16* ub;
  const float* resid; float* outp;
  __hip_bfloat16* Cb; int ldc;
  float* f32o; __hip_bfloat16* bf16o;
};

__device__ __forceinline__ void xcd_swz(int& bx, int& by) {
  const int gx = gridDim.x;
  const int nwg = gx*gridDim.y;
  const int lin = by*gx + bx;
  const int qq = nwg >> 3, rr = nwg & 7;
  const int xcd = lin & 7, pos = lin >> 3;
  const int base = (xcd < rr) ? xcd*(qq+1) : rr*(qq+1) + (xcd-rr)*qq;
  const int lg = base + pos;
  bx = lg % gx; by = lg / gx;
}

#define MBM 128
#define MBK 64

template<int EPI, bool TRIK, bool SWZ>
__global__ __launch_bounds__(256, 4) void mgemm_k(
    const __hip_bfloat16* __restrict__ A, int lda, long long sAz,
    const __hip_bfloat16* __restrict__ B, int ldb, long long sBz,
    int K, MEp ep)
{
  __shared__ __attribute__((aligned(16))) short As[MBM*MBK];
  __shared__ __attribute__((aligned(16))) short Bs[MBM*MBK];
  const int tid = threadIdx.x;
  const int wv = tid>>6, lane = tid&63;
  const int z = blockIdx.z;
  A += (size_t)z * sAz;
  B += (size_t)z * sBz;
  int bx = blockIdx.x, by = blockIdx.y;
  if constexpr (SWZ) xcd_swz(bx, by);
  const int m0 = by*MBM, n0 = bx*MBM;
  if constexpr (EPI==2) { if (n0 > m0 + (MBM-1)) return; }
  const int r8 = lane>>3, g8 = lane&7;
  const int csrc = g8 ^ r8;
  const int wr = wv>>1, wc = wv&1;
  const int fr = lane&15, qv = lane>>4;
  const int x7 = fr & 7;

  int Ktot = K;
  if constexpr (TRIK) { int km = m0 + MBM; Ktot = km < K ? km : K; }
  const int nt = Ktot / MBK;

  f32x4 acc[4][4] = {};

  const __hip_bfloat16* Ag = A + (size_t)(m0 + wv*32 + r8)*lda + csrc*8;
  const __hip_bfloat16* Bg = B + (size_t)(n0 + wv*32 + r8)*ldb + csrc*8;

  auto stage = [&](int t){
    const int k0 = t*MBK;
    short* Al = &As[wv*32*MBK];
    short* Bl = &Bs[wv*32*MBK];
    #pragma unroll
    for (int j=0;j<4;++j)
      gload_lds16(Ag + (size_t)(j*8)*lda + k0, Al + j*8*MBK);
    #pragma unroll
    for (int j=0;j<4;++j)
      gload_lds16(Bg + (size_t)(j*8)*ldb + k0, Bl + j*8*MBK);
  };

  for (int t=0; t<nt; ++t) {
    stage(t);
    __syncthreads();                          // drains vmcnt; tile ready on all waves
    #pragma unroll
    for (int kk=0; kk<2; ++kk) {
      const int pos8 = ((kk*4 + qv) ^ x7) * 8;
      bf16x8 af[4], bfr[4];
      #pragma unroll
      for (int mi=0;mi<4;++mi)
        af[mi] = *(const bf16x8*)&As[(wr*64 + mi*16 + fr)*MBK + pos8];
      #pragma unroll
      for (int ni=0;ni<4;++ni)
        bfr[ni] = *(const bf16x8*)&Bs[(wc*64 + ni*16 + fr)*MBK + pos8];
      #pragma unroll
      for (int mi=0;mi<4;++mi)
        #pragma unroll
        for (int ni=0;ni<4;++ni)
          acc[mi][ni] = __builtin_amdgcn_mfma_f32_16x16x32_bf16(af[mi], bfr[ni], acc[mi][ni], 0,0,0);
    }
    if (t+1 < nt) __syncthreads();            // all waves done reading before overwrite
  }

  const int vr = (lane>>4)*4;
  #pragma unroll
  for (int mi=0;mi<4;++mi) {
    #pragma unroll
    for (int v=0; v<4; ++v) {
      const int row = m0 + wr*64 + mi*16 + vr + v;
      #pragma unroll
      for (int ni=0;ni<4;++ni) {
        const int col = n0 + wc*64 + ni*16 + fr;
        float val = acc[mi][ni][v];
        if constexpr (EPI==1) {
          val += ep.bias[col];
          if (col < 1024) {
            ep.ug[(size_t)row*EMBED + col] = tobf(sigmoidf_(val));
          } else if (col < 1152) {
            int jj = col - 1024;
            float zz = siluf_(val);
            ep.qo[(size_t)row*ZD + jj] = tobf((zz*ep.gamma[jj] + ep.beta2[jj]) * 0.08838834764831845f);
            ep.ko[(size_t)row*ZD + jj] = tobf(zz*ep.gamma[128+jj] + ep.beta2[128+jj]);
          } else if (col < 2176) {
            ep.ro[(size_t)row*EMBED + (col-1152)] = tobf(siluf_(val));
          } else {
            ep.hxo[(size_t)row*EMBED + (col-2176)] = tobf(val);
          }
        } else if constexpr (EPI==2) {
          __hip_bfloat16* Sp = ep.Cb + (size_t)z*CHUNKC*CHUNKC;
          if (col <= row) Sp[(size_t)row*CHUNKC + col] = tobf(val + ep.gtab[row-col]);
        } else if constexpr (EPI==3) {
          size_t gr = (size_t)z*CHUNKC + row;
          ep.Cb[gr*EMBED + col] = tobf(val * frombf(ep.rb[gr*EMBED + col]));
        } else if constexpr (EPI==4) {
          float zz = val + ep.bias[col] + frombf(ep.hxb[(size_t)row*EMBED + col]);
          float hh = siluf_(zz);
          float res = ep.resid[(size_t)row*EMBED + col];
          ep.outp[(size_t)row*EMBED + col] = res + frombf(ep.ub[(size_t)row*EMBED + col])*(hh-res);
        } else if constexpr (EPI==6) {
          float zv = val + ep.bias[col];
          ep.bf16o[(size_t)row*EMBED + col] = tobf((zv > 15.f) ? zv : log1pf(__expf(zv)));
        } else {  // EPI==7: v (cols<1024) + xdbl ride-along: dt-input bf16 (64) + compact B/C f32 (32)
          if (col < 1024) {
            ep.Cb[(size_t)row*ep.ldc + col] = tobf(siluf_(val + ep.bias[col]));
          } else {
            int jj = col - 1024;
            if (jj < DTR)          ep.bf16o[(size_t)row*DTR + jj] = tobf(val);
            else if (jj < XDBL_W)  ep.f32o[(size_t)row*32 + (jj - DTR)] = val;
          }
        }
      }
    }
  }
}

// ---------------------------------------------------------------- launch
extern "C" void kernel_launch(void* const* d_in, const int* in_sizes, int n_in,
                              void* d_out, int out_size, void* d_ws, size_t ws_size,
                              hipStream_t stream) {
  const float* x       = (const float*)d_in[0];
  const float* norm_w  = (const float*)d_in[1];
  const float* v_w     = (const float*)d_in[2];
  const float* v_b     = (const float*)d_in[3];
  const float* mx_w    = (const float*)d_in[4];
  const float* mx_b    = (const float*)d_in[5];
  const float* h_w     = (const float*)d_in[6];
  const float* h_b     = (const float*)d_in[7];
  const float* gamma   = (const float*)d_in[8];
  const float* beta    = (const float*)d_in[9];
  const float* alpha_rb= (const float*)d_in[10];
  const float* beta_rb = (const float*)d_in[11];
  const float* xproj_w = (const float*)d_in[12];
  const float* dt_w    = (const float*)d_in[13];
  const float* dt_b    = (const float*)d_in[14];
  const float* A_log   = (const float*)d_in[15];
  const float* D_p     = (const float*)d_in[16];
  float* out = (float*)d_out;

  float* ws = (float*)d_ws;
  size_t off = 0;
  auto alloc = [&](size_t n){ float* p = ws + off; off += n; return p; };
  const size_t BL2 = (size_t)BATCH*LSEQ; // 8192

  float* sbzone  = alloc(BL2*EMBED);        // Sb (bf16 4*2048*2048) lives here
  float* scratch = alloc((size_t)2*CHUNKC*CHUNKC*2); // dtbb+seg*, then S(bf16)
  float* xbc     = alloc(BL2*32);           // compact B/C f32 [row][32]
  float* gtab    = alloc(CHUNKC);
  auto balloc = [&](size_t nbf){ __hip_bfloat16* p = (__hip_bfloat16*)(ws + off); off += (nbf+1)/2; return p; };
  __hip_bfloat16* xnb   = balloc(BL2*EMBED);   // later reused as VT (after scan)
  __hip_bfloat16* vbufb = balloc(BL2*EMBED);
  __hip_bfloat16* mxb   = balloc(BL2*EMBED);
  __hip_bfloat16* qb    = balloc(BL2*ZD);
  __hip_bfloat16* kb    = balloc(BL2*ZD);
  __hip_bfloat16* ugb   = balloc(BL2*EMBED);
  __hip_bfloat16* rbb   = balloc(BL2*EMBED);
  __hip_bfloat16* hxbb  = balloc(BL2*EMBED);
  __hip_bfloat16* hrb   = balloc(BL2*EMBED);
  __hip_bfloat16* xdblb = balloc(BL2*DTR);
  __hip_bfloat16* wcat  = balloc((size_t)1152*EMBED);  // [v_w(1024); xproj_w(96); pad(32)]
  __hip_bfloat16* mxwb  = balloc((size_t)3200*EMBED);
  __hip_bfloat16* hwb   = balloc((size_t)EMBED*EMBED);
  __hip_bfloat16* dtwb  = balloc((size_t)EMBED*DTR);

  __hip_bfloat16* dtbb = (__hip_bfloat16*)scratch;     // bf16 [BL2][EMBED]
  float* segP    = scratch + BL2*EMBED;
  float* segH    = segP + (size_t)NSEG*2048*NSTATE;
  float* segInit = segH + (size_t)NSEG*2048*NSTATE;
  __hip_bfloat16* S  = (__hip_bfloat16*)scratch;  // after scan (bf16 4*2048*2048)
  __hip_bfloat16* Sb = (__hip_bfloat16*)sbzone;   // after scan
  __hip_bfloat16* VT = xnb;                       // after scan pass 3

  // 0. unified prep: all weight converts + pad + gtab
  prep_k<<<5448, 256, 0, stream>>>(v_w, xproj_w, h_w, dt_w, mx_w,
                                   alpha_rb, beta_rb,
                                   wcat, hwb, dtwb, mxwb, gtab);

  // 1. rmsnorm (bf16 only)
  rmsnorm_k<<<(int)BL2, 256, 0, stream>>>(x, norm_w, xnb);

  MEp ep;

  // 2. v = silu(xn @ v_w^T + v_b) [cols<1024] + dt-input bf16 + compact B/C [cols 1024..1119]
  ep = {}; ep.bias = v_b; ep.Cb = vbufb; ep.ldc = EMBED;
  ep.f32o = xbc; ep.bf16o = xdblb;
  mgemm_k<7,false,true><<<dim3(1152/MBM, BL2/MBM), 256, 0, stream>>>(
      xnb, EMBED, 0, wcat, EMBED, 0, EMBED, ep);

  // 3. dt = softplus(xdbl[:, :64] @ dt_w^T + dt_b)  (bf16 out)
  ep = {}; ep.bias = dt_b; ep.bf16o = dtbb;
  mgemm_k<6,false,true><<<dim3(EMBED/MBM, BL2/MBM), 256, 0, stream>>>(
      xdblb, DTR, 0, dtwb, DTR, 0, DTR, ep);

  // 4. segment-parallel scan -> mxb (reads bf16 dt/u + compact f32 B/C)
  seg_scan_k<false><<<NSEG*8, 256, 0, stream>>>(xbc, dtbb, xnb, A_log, D_p,
                                                nullptr, segP, segH, nullptr);
  seg_combine_k<<<128, 256, 0, stream>>>(segP, segH, segInit);
  seg_scan_k<true><<<NSEG*8, 256, 0, stream>>>(xbc, dtbb, xnb, A_log, D_p,
                                               segInit, nullptr, nullptr, mxb);

  // 4b. transpose V per chunk (xnb dead now -> VT)
  transpose_k<<<dim3(EMBED/64, BL2/64), 256, 0, stream>>>(
      (const unsigned short*)vbufb, (unsigned short*)VT);

  // 5. base = mx @ mx_w^T + mx_b, split epilogue
  ep = {}; ep.bias = mx_b; ep.gamma = gamma; ep.beta2 = beta;
  ep.ug = ugb; ep.qo = qb; ep.ko = kb; ep.ro = rbb; ep.hxo = hxbb;
  mgemm_k<1,false,true><<<dim3(3200/MBM, BL2/MBM), 256, 0, stream>>>(
      mxb, EMBED, 0, mxwb, EMBED, 0, EMBED, ep);

  // 6. QK^T + bias + mask -> bf16 S (upper-triangle tiles + stores skipped)
  ep = {}; ep.gtab = gtab; ep.Cb = S;
  mgemm_k<2,false,true><<<dim3(CHUNKC/MBM, CHUNKC/MBM, 4), 256, 0, stream>>>(
      qb, ZD, (long long)CHUNKC*ZD, kb, ZD, (long long)CHUNKC*ZD, ZD, ep);

  // 7. softmax (causal reads, writes clipped to PV-visible cols)
  softmax_k<<<4*CHUNKC, 256, 0, stream>>>(S, Sb);

  // 8. P@V, K clipped to diagonal, fused *r -> bf16
  ep = {}; ep.rb = rbb; ep.Cb = hrb;
  mgemm_k<3,true,true><<<dim3(EMBED/MBM, CHUNKC/MBM, 4), 256, 0, stream>>>(
      Sb, CHUNKC, (long long)CHUNKC*CHUNKC, VT, CHUNKC, (long long)EMBED*CHUNKC, CHUNKC, ep);

  // 9. final: h = silu(hx + (h*r) @ h_w^T + h_b); out = x + u*(h-x)
  ep = {}; ep.bias = h_b; ep.hxb = hxbb; ep.ub = ugb; ep.resid = x; ep.outp = out;
  mgemm_k<4,false,true><<<dim3(EMBED/MBM, BL2/MBM), 256, 0, stream>>>(
      hrb, EMBED, 0, hwb, EMBED, 0, EMBED, ep);
}